// Round 3
// baseline (18588.300 us; speedup 1.0000x reference)
//
#include <hip/hip_runtime.h>
#include <hip/hip_bf16.h>
#include <cstdint>
#include <cstddef>

static constexpr int FD = 128;   // feature dim
static constexpr int NG = 16;    // graphs per batch
static constexpr int NL = 3;     // layers

// ---------------- CSR build ----------------
__global__ void k_count_deg(const int* __restrict__ edges, int* __restrict__ deg, int E) {
  int e = blockIdx.x * blockDim.x + threadIdx.x;
  if (e < E) atomicAdd(&deg[edges[E + e]], 1);
}

// single-block scan: wave shfl-scan, 4 elems/thread, few barriers
__global__ __launch_bounds__(1024) void k_scan(const int* __restrict__ deg,
                                               int* __restrict__ off,
                                               int* __restrict__ wptr, int n) {
  __shared__ int wsum[16];
  __shared__ int carry_s;
  int tid = (int)threadIdx.x;
  int lane = tid & 63;
  int wave = tid >> 6;
  if (tid == 0) carry_s = 0;
  __syncthreads();
  for (int base = 0; base < n; base += 4096) {
    int i0 = base + tid * 4;
    int v[4];
    int s = 0;
    #pragma unroll
    for (int j = 0; j < 4; j++) { v[j] = (i0 + j < n) ? deg[i0 + j] : 0; s += v[j]; }
    int sc = s;
    #pragma unroll
    for (int d = 1; d < 64; d <<= 1) {
      int t = __shfl_up(sc, d, 64);
      if (lane >= d) sc += t;
    }
    if (lane == 63) wsum[wave] = sc;
    __syncthreads();
    if (wave == 0 && lane < 16) {
      int ws = wsum[lane];
      int wsc = ws;
      #pragma unroll
      for (int d = 1; d < 16; d <<= 1) {
        int t = __shfl_up(wsc, d, 64);
        if (lane >= d) wsc += t;
      }
      wsum[lane] = wsc - ws;   // exclusive wave prefix
    }
    __syncthreads();
    int excl = carry_s + wsum[wave] + (sc - s);
    #pragma unroll
    for (int j = 0; j < 4; j++) {
      if (i0 + j < n) { off[i0 + j] = excl; wptr[i0 + j] = excl; }
      excl += v[j];
    }
    __syncthreads();
    if (tid == 1023) carry_s += wsum[15] + sc;   // chunk total
    __syncthreads();
  }
}

__global__ void k_fill_csr(const int* __restrict__ edges, int* __restrict__ wptr,
                           int* __restrict__ csr, int E) {
  int e = blockIdx.x * blockDim.x + threadIdx.x;
  if (e < E) {
    int s = edges[e];          // src
    int d = edges[E + e];      // dst
    int pos = atomicAdd(&wptr[d], 1);
    csr[pos] = s;
  }
}

// ---------------- fused SAGE layer: y = relu(mean_N(x)@Wl + x@Wr + b) ----------------
// 64-row tile per block, 256 threads. AB[0]=gathered mean tile, AB[1]=x tile
// (async-staged). W staged in 32x128 LDS chunks with register ping-pong
// prefetch. Inner loop is pure LDS->FMA.
__global__ __launch_bounds__(256) void k_sage(
    const float* __restrict__ x,
    const int* __restrict__ csr, const int* __restrict__ off,
    const int* __restrict__ deg,
    const float* __restrict__ Wl, const float* __restrict__ Wr,
    const float* __restrict__ bias, float* __restrict__ out, int n)
{
  __shared__ float AB[2][64][FD];   // 64 KB
  __shared__ float Ws[32][FD];      // 16 KB
  int tid = (int)threadIdx.x;
  int tx = tid & 31;                // col group (cols tx*4..tx*4+3)
  int ty = tid >> 5;                // row group (8 rows each)
  int row0 = blockIdx.x * 64;

  // ---- phase 0: async-stage x tile (rows row0..row0+63) into AB[1] ----
  if (row0 + 64 <= n) {
    int wv = tid >> 6, ln = tid & 63;
    const float* gbase = x + (size_t)row0 * FD;
    #pragma unroll
    for (int j = 0; j < 8; j++) {
      int foff = (j * 4 + wv) * 256 + ln * 4;   // float offset; wave stages 1KB
      __builtin_amdgcn_global_load_lds(
          (const __attribute__((address_space(1))) void*)(gbase + foff),
          (__attribute__((address_space(3))) void*)(&AB[1][0][0] + foff),
          16, 0, 0);
    }
  } else {
    #pragma unroll
    for (int j = 0; j < 8; j++) {
      int r = j * 8 + ty;
      int row = row0 + r;
      float4 v = make_float4(0.f, 0.f, 0.f, 0.f);
      if (row < n) v = *(const float4*)&x[(size_t)row * FD + tx * 4];
      *(float4*)&AB[1][r][tx * 4] = v;
    }
  }

  // ---- phase 1: gather-mean into AB[0] (overlaps async stage) ----
  for (int j = 0; j < 8; j++) {
    int r = ty * 8 + j;
    int row = row0 + r;
    float4 acc = make_float4(0.f, 0.f, 0.f, 0.f);
    if (row < n) {
      int o = off[row];
      int d = deg[row];
      int c4 = tx * 4;
      int k = 0;
      for (; k + 4 <= d; k += 4) {
        int s0 = csr[o + k + 0];
        int s1 = csr[o + k + 1];
        int s2 = csr[o + k + 2];
        int s3 = csr[o + k + 3];
        float4 v0 = *(const float4*)&x[(size_t)s0 * FD + c4];
        float4 v1 = *(const float4*)&x[(size_t)s1 * FD + c4];
        float4 v2 = *(const float4*)&x[(size_t)s2 * FD + c4];
        float4 v3 = *(const float4*)&x[(size_t)s3 * FD + c4];
        acc.x += (v0.x + v1.x) + (v2.x + v3.x);
        acc.y += (v0.y + v1.y) + (v2.y + v3.y);
        acc.z += (v0.z + v1.z) + (v2.z + v3.z);
        acc.w += (v0.w + v1.w) + (v2.w + v3.w);
      }
      for (; k < d; k++) {
        int s = csr[o + k];
        float4 v = *(const float4*)&x[(size_t)s * FD + c4];
        acc.x += v.x; acc.y += v.y; acc.z += v.z; acc.w += v.w;
      }
      float inv = 1.f / fmaxf((float)d, 1.f);
      acc.x *= inv; acc.y *= inv; acc.z *= inv; acc.w *= inv;
    }
    *(float4*)&AB[0][r][tx * 4] = acc;
  }

  // ---- phase 2: GEMM from LDS; W chunks via register ping-pong ----
  const float* const Whalf[2] = {Wl, Wr};
  float4 wreg[4];
  #pragma unroll
  for (int q = 0; q < 4; q++) {          // prefetch chunk 0 (Wl rows 0..31)
    int f = q * 256 + tid;
    wreg[q] = *(const float4*)&Wl[(size_t)(f >> 5) * FD + (f & 31) * 4];
  }

  float acc[8][4];
  #pragma unroll
  for (int r = 0; r < 8; r++)
    #pragma unroll
    for (int c = 0; c < 4; c++) acc[r][c] = 0.f;
  int r0l = ty * 8;

  #pragma unroll
  for (int half = 0; half < 2; half++) {
    #pragma unroll
    for (int kcb = 0; kcb < 4; kcb++) {
      int kc = kcb * 32;
      __syncthreads();                   // Ws free; first pass: stage+gather done
      #pragma unroll
      for (int q = 0; q < 4; q++) {
        int f = q * 256 + tid;
        *(float4*)&Ws[f >> 5][(f & 31) * 4] = wreg[q];
      }
      int nc = half * 4 + kcb + 1;       // prefetch next chunk while computing
      if (nc < 8) {
        const float* W = Whalf[nc >> 2] + (size_t)(nc & 3) * 32 * FD;
        #pragma unroll
        for (int q = 0; q < 4; q++) {
          int f = q * 256 + tid;
          wreg[q] = *(const float4*)&W[(size_t)(f >> 5) * FD + (f & 31) * 4];
        }
      }
      __syncthreads();                   // Ws ready
      #pragma unroll
      for (int k4 = 0; k4 < 32; k4 += 4) {
        float4 a4[8];
        #pragma unroll
        for (int r = 0; r < 8; r++)
          a4[r] = *(const float4*)&AB[half][r0l + r][kc + k4];
        #pragma unroll
        for (int kk = 0; kk < 4; kk++) {
          float4 w4 = *(const float4*)&Ws[k4 + kk][tx * 4];
          #pragma unroll
          for (int r = 0; r < 8; r++) {
            float a = (kk == 0) ? a4[r].x : (kk == 1) ? a4[r].y
                    : (kk == 2) ? a4[r].z : a4[r].w;
            acc[r][0] = fmaf(a, w4.x, acc[r][0]);
            acc[r][1] = fmaf(a, w4.y, acc[r][1]);
            acc[r][2] = fmaf(a, w4.z, acc[r][2]);
            acc[r][3] = fmaf(a, w4.w, acc[r][3]);
          }
        }
      }
    }
  }

  float4 b4 = *(const float4*)&bias[tx * 4];
  #pragma unroll
  for (int r = 0; r < 8; r++) {
    int row = row0 + r0l + r;
    if (row < n) {
      float4 o;
      o.x = fmaxf(acc[r][0] + b4.x, 0.f);
      o.y = fmaxf(acc[r][1] + b4.y, 0.f);
      o.z = fmaxf(acc[r][2] + b4.z, 0.f);
      o.w = fmaxf(acc[r][3] + b4.w, 0.f);
      *(float4*)&out[(size_t)row * FD + tx * 4] = o;
    }
  }
}

// ---------------- graph mean-pool: 128 rows/block, float4, run-flush atomics ----------------
__global__ __launch_bounds__(256) void k_pool(
    const float* __restrict__ x, const int* __restrict__ batch,
    float* __restrict__ pool, float* __restrict__ pcnt, int n) {
  int tid = (int)threadIdx.x;
  int c4 = (tid & 31) * 4;
  int rs = tid >> 5;
  int start = blockIdx.x * 128;
  int end = min(start + 128, n);
  if (start >= end) return;

  float4 acc = make_float4(0.f, 0.f, 0.f, 0.f);
  float cnt = 0.f;
  auto flush = [&](int g) {
    atomicAdd(&pool[g * FD + c4 + 0], acc.x);
    atomicAdd(&pool[g * FD + c4 + 1], acc.y);
    atomicAdd(&pool[g * FD + c4 + 2], acc.z);
    atomicAdd(&pool[g * FD + c4 + 3], acc.w);
    if ((tid & 31) == 0) atomicAdd(&pcnt[g], cnt);
  };

  int gfirst = batch[start];
  int glast = batch[end - 1];
  if (gfirst == glast) {
    for (int i = start + rs; i < end; i += 8) {
      float4 v = *(const float4*)&x[(size_t)i * FD + c4];
      acc.x += v.x; acc.y += v.y; acc.z += v.z; acc.w += v.w;
      cnt += 1.f;
    }
    flush(gfirst);
  } else {
    int curg = -1;
    for (int i = start + rs; i < end; i += 8) {
      int g = batch[i];
      if (g != curg) {
        if (curg >= 0) flush(curg);
        curg = g;
        acc = make_float4(0.f, 0.f, 0.f, 0.f);
        cnt = 0.f;
      }
      float4 v = *(const float4*)&x[(size_t)i * FD + c4];
      acc.x += v.x; acc.y += v.y; acc.z += v.z; acc.w += v.w;
      cnt += 1.f;
    }
    if (curg >= 0) flush(curg);
  }
}

// ---------------- head ----------------
__global__ void k_final(const float* __restrict__ pool, const float* __restrict__ pcnt,
                        const float* __restrict__ linW, const float* __restrict__ linb,
                        float* __restrict__ out) {
  int tid = (int)threadIdx.x;
  if (tid < NG * 2) {
    int g = tid >> 1, o = tid & 1;
    float s = linb[o];
    for (int t = 0; t < 2; t++) {
      float inv = 1.f / fmaxf(pcnt[t * NG + g], 1.f);
      for (int d = 0; d < FD; d++) {
        float h = pool[(t * NG + g) * FD + d] * inv;
        s = fmaf(h, linW[(t * FD + d) * 2 + o], s);
      }
    }
    out[g * 2 + o] = s;
  }
}

extern "C" void kernel_launch(void* const* d_in, const int* in_sizes, int n_in,
                              void* d_out, int out_size, void* d_ws, size_t ws_size,
                              hipStream_t stream) {
  const float* x_in[2] = {(const float*)d_in[0], (const float*)d_in[1]};
  const float* Wl   = (const float*)d_in[2];
  const float* bl   = (const float*)d_in[3];
  const float* Wr   = (const float*)d_in[4];
  const float* linW = (const float*)d_in[5];
  const float* linb = (const float*)d_in[6];
  const int* edges[2] = {(const int*)d_in[7], (const int*)d_in[8]};
  const int* batch[2] = {(const int*)d_in[9], (const int*)d_in[10]};

  const int N = in_sizes[0] / FD;    // 50000
  const int E = in_sizes[7] / 2;     // 800000

  // ---- workspace layout (512B aligned) ----
  char* p = (char*)d_ws;
  auto alloc = [&](size_t bytes) -> char* {
    char* r = p; p += (bytes + 511) & ~(size_t)511; return r;
  };
  int* deg[2];  deg[0]  = (int*)alloc((size_t)N * 4); deg[1]  = (int*)alloc((size_t)N * 4);
  float* pool  = (float*)alloc(2 * NG * FD * 4);
  float* pcnt  = (float*)alloc(2 * NG * 4);
  size_t zero_bytes = (size_t)(p - (char*)d_ws);       // deg+pool+pcnt need zeroing
  int* off[2];  off[0]  = (int*)alloc((size_t)N * 4); off[1]  = (int*)alloc((size_t)N * 4);
  int* wptr[2]; wptr[0] = (int*)alloc((size_t)N * 4); wptr[1] = (int*)alloc((size_t)N * 4);
  int* csr[2];  csr[0]  = (int*)alloc((size_t)E * 4); csr[1]  = (int*)alloc((size_t)E * 4);
  float* xbuf[2][2];
  for (int t = 0; t < 2; t++)
    for (int b = 0; b < 2; b++) xbuf[t][b] = (float*)alloc((size_t)N * FD * 4);
  if ((size_t)(p - (char*)d_ws) > ws_size) return;     // insufficient workspace

  hipMemsetAsync(d_ws, 0, zero_bytes, stream);

  int eb = (E + 255) / 256;
  for (int t = 0; t < 2; t++) k_count_deg<<<eb, 256, 0, stream>>>(edges[t], deg[t], E);
  for (int t = 0; t < 2; t++) k_scan<<<1, 1024, 0, stream>>>(deg[t], off[t], wptr[t], N);
  for (int t = 0; t < 2; t++) k_fill_csr<<<eb, 256, 0, stream>>>(edges[t], wptr[t], csr[t], E);

  int gblocks = (N + 63) / 64;
  const float* cur[2] = {x_in[0], x_in[1]};
  int pp = 0;
  for (int l = 0; l < NL; l++) {
    for (int t = 0; t < 2; t++) {
      int wi = l * 2 + t;
      float* nxt = xbuf[t][pp];
      k_sage<<<gblocks, 256, 0, stream>>>(
          cur[t], csr[t], off[t], deg[t],
          Wl + (size_t)wi * FD * FD, Wr + (size_t)wi * FD * FD,
          bl + (size_t)wi * FD, nxt, N);
      cur[t] = nxt;
    }
    pp ^= 1;
  }

  int pblocks = (N + 127) / 128;
  for (int t = 0; t < 2; t++)
    k_pool<<<pblocks, 256, 0, stream>>>(cur[t], batch[t], pool + t * NG * FD, pcnt + t * NG, N);
  k_final<<<1, 64, 0, stream>>>(pool, pcnt, linW, linb, (float*)d_out);
}

// Round 4
// 1228.454 us; speedup vs baseline: 15.1315x; 15.1315x over previous
//
#include <hip/hip_runtime.h>
#include <hip/hip_bf16.h>
#include <cstdint>
#include <cstddef>

static constexpr int FD = 128;   // feature dim
static constexpr int NG = 16;    // graphs per batch
static constexpr int NL = 3;     // layers

// ---------------- CSR build (both types per launch) ----------------
__global__ void k_count_deg(const int* __restrict__ e0, const int* __restrict__ e1,
                            int* __restrict__ d0, int* __restrict__ d1, int E) {
  int i = blockIdx.x * blockDim.x + threadIdx.x;
  if (i < E) atomicAdd(&d0[e0[E + i]], 1);
  else if (i < 2 * E) atomicAdd(&d1[e1[E + (i - E)]], 1);
}

// 2-block scan: block b handles type b. wave shfl-scan, 4 elems/thread.
__global__ __launch_bounds__(1024) void k_scan(
    const int* __restrict__ dg0, const int* __restrict__ dg1,
    int* __restrict__ of0, int* __restrict__ of1,
    int* __restrict__ wp0, int* __restrict__ wp1, int n) {
  const int* deg = blockIdx.x ? dg1 : dg0;
  int* off = blockIdx.x ? of1 : of0;
  int* wptr = blockIdx.x ? wp1 : wp0;
  __shared__ int wsum[16];
  __shared__ int carry_s;
  int tid = (int)threadIdx.x;
  int lane = tid & 63;
  int wave = tid >> 6;
  if (tid == 0) carry_s = 0;
  __syncthreads();
  for (int base = 0; base < n; base += 4096) {
    int i0 = base + tid * 4;
    int v[4];
    int s = 0;
    #pragma unroll
    for (int j = 0; j < 4; j++) { v[j] = (i0 + j < n) ? deg[i0 + j] : 0; s += v[j]; }
    int sc = s;
    #pragma unroll
    for (int d = 1; d < 64; d <<= 1) {
      int t = __shfl_up(sc, d, 64);
      if (lane >= d) sc += t;
    }
    if (lane == 63) wsum[wave] = sc;
    __syncthreads();
    if (wave == 0 && lane < 16) {
      int ws = wsum[lane];
      int wsc = ws;
      #pragma unroll
      for (int d = 1; d < 16; d <<= 1) {
        int t = __shfl_up(wsc, d, 64);
        if (lane >= d) wsc += t;
      }
      wsum[lane] = wsc - ws;   // exclusive wave prefix
    }
    __syncthreads();
    int excl = carry_s + wsum[wave] + (sc - s);
    #pragma unroll
    for (int j = 0; j < 4; j++) {
      if (i0 + j < n) { off[i0 + j] = excl; wptr[i0 + j] = excl; }
      excl += v[j];
    }
    __syncthreads();
    if (tid == 1023) carry_s += wsum[15] + sc;   // chunk total
    __syncthreads();
  }
}

__global__ void k_fill_csr(const int* __restrict__ e0, const int* __restrict__ e1,
                           int* __restrict__ w0, int* __restrict__ w1,
                           int* __restrict__ c0, int* __restrict__ c1, int E) {
  int i = blockIdx.x * blockDim.x + threadIdx.x;
  if (i < E) {
    int pos = atomicAdd(&w0[e0[E + i]], 1);
    c0[pos] = e0[i];
  } else if (i < 2 * E) {
    int j = i - E;
    int pos = atomicAdd(&w1[e1[E + j]], 1);
    c1[pos] = e1[j];
  }
}

// ---------------- neighbor mean: both types; coalesced csr + shfl broadcast ----------------
__global__ __launch_bounds__(256) void k_agg(
    const float* __restrict__ x0, const float* __restrict__ x1,
    const int* __restrict__ csr0, const int* __restrict__ csr1,
    const int* __restrict__ off0, const int* __restrict__ off1,
    const int* __restrict__ deg0, const int* __restrict__ deg1,
    float* __restrict__ m0, float* __restrict__ m1, int n)
{
  int bx = blockIdx.x;
  int t = bx & 1;
  int node = (bx >> 1) * 8 + ((int)threadIdx.x >> 5);
  if (node >= n) return;
  const float* x  = t ? x1 : x0;
  const int* csr  = t ? csr1 : csr0;
  const int* off  = t ? off1 : off0;
  const int* deg  = t ? deg1 : deg0;
  float* mean     = t ? m1 : m0;
  int tx = (int)threadIdx.x & 31;
  int c4 = tx * 4;
  int o = off[node], d = deg[node];
  float4 acc = make_float4(0.f, 0.f, 0.f, 0.f);
  for (int k0 = 0; k0 < d; k0 += 32) {
    int idx = (k0 + tx < d) ? csr[o + k0 + tx] : 0;   // one coalesced 128B read / 32 edges
    int m = min(32, d - k0);
    int j = 0;
    for (; j + 8 <= m; j += 8) {
      int s0 = __shfl(idx, j + 0, 32);
      int s1 = __shfl(idx, j + 1, 32);
      int s2 = __shfl(idx, j + 2, 32);
      int s3 = __shfl(idx, j + 3, 32);
      int s4 = __shfl(idx, j + 4, 32);
      int s5 = __shfl(idx, j + 5, 32);
      int s6 = __shfl(idx, j + 6, 32);
      int s7 = __shfl(idx, j + 7, 32);
      float4 v0 = *(const float4*)&x[(size_t)s0 * FD + c4];
      float4 v1 = *(const float4*)&x[(size_t)s1 * FD + c4];
      float4 v2 = *(const float4*)&x[(size_t)s2 * FD + c4];
      float4 v3 = *(const float4*)&x[(size_t)s3 * FD + c4];
      float4 v4 = *(const float4*)&x[(size_t)s4 * FD + c4];
      float4 v5 = *(const float4*)&x[(size_t)s5 * FD + c4];
      float4 v6 = *(const float4*)&x[(size_t)s6 * FD + c4];
      float4 v7 = *(const float4*)&x[(size_t)s7 * FD + c4];
      acc.x += ((v0.x + v1.x) + (v2.x + v3.x)) + ((v4.x + v5.x) + (v6.x + v7.x));
      acc.y += ((v0.y + v1.y) + (v2.y + v3.y)) + ((v4.y + v5.y) + (v6.y + v7.y));
      acc.z += ((v0.z + v1.z) + (v2.z + v3.z)) + ((v4.z + v5.z) + (v6.z + v7.z));
      acc.w += ((v0.w + v1.w) + (v2.w + v3.w)) + ((v4.w + v5.w) + (v6.w + v7.w));
    }
    for (; j < m; j++) {
      int s = __shfl(idx, j, 32);
      float4 v = *(const float4*)&x[(size_t)s * FD + c4];
      acc.x += v.x; acc.y += v.y; acc.z += v.z; acc.w += v.w;
    }
  }
  float inv = 1.f / fmaxf((float)d, 1.f);
  float4 o4 = make_float4(acc.x * inv, acc.y * inv, acc.z * inv, acc.w * inv);
  *(float4*)&mean[(size_t)node * FD + c4] = o4;
}

// ---------------- GEMM: y = relu(mean@Wl + x@Wr + b), both types per launch ----------------
// 64-row tile, 256 threads. A-chunk (64x32, 8KB) and W-chunk (32x128, 16KB)
// double-buffered in LDS via async global_load_lds; stage(c+1) issued right
// after barrier(c) so it overlaps compute(c). Inner loop pure LDS->FMA.
__global__ __launch_bounds__(256) void k_gemm(
    const float* __restrict__ Am0, const float* __restrict__ Am1,
    const float* __restrict__ Ax0, const float* __restrict__ Ax1,
    const float* __restrict__ Wl, const float* __restrict__ Wr,   // layer base [2][D][D]
    const float* __restrict__ bl,                                  // layer base [2][D]
    float* __restrict__ out0, float* __restrict__ out1, int n)
{
  __shared__ float As[2][64][32];    // 16 KB
  __shared__ float Wsb[2][32][FD];   // 32 KB
  int tid = (int)threadIdx.x;
  int tx = tid & 31;
  int ty = tid >> 5;
  int wv = tid >> 6, ln = tid & 63;
  int bx = (int)blockIdx.x;
  int t = bx & 1;
  int row0 = (bx >> 1) * 64;
  int nm1 = n - 1;

  const float* Asrcs[2] = { t ? Am1 : Am0, t ? Ax1 : Ax0 };
  const float* Wsrcs[2] = { Wl + (size_t)t * FD * FD, Wr + (size_t)t * FD * FD };
  const float* bias = bl + (size_t)t * FD;
  float* out = t ? out1 : out0;

  auto stage = [&](int c, int buf) {
    const float* A = Asrcs[c >> 2];
    int kc = (c & 3) * 32;
    #pragma unroll
    for (int i = 0; i < 2; i++) {               // A: wave stages 16 rows (8/issue)
      int row = row0 + wv * 16 + i * 8 + (ln >> 3);
      if (row > nm1) row = nm1;
      const float* g = A + (size_t)row * FD + kc + (ln & 7) * 4;
      __builtin_amdgcn_global_load_lds(
          (const __attribute__((address_space(1))) void*)g,
          (__attribute__((address_space(3))) void*)&As[buf][wv * 16 + i * 8][0],
          16, 0, 0);
    }
    const float* W = Wsrcs[c >> 2] + (size_t)kc * FD;   // 16 KB contiguous chunk
    #pragma unroll
    for (int i = 0; i < 4; i++) {               // W: wave stages 4 KB (1KB/issue)
      int foff = wv * 1024 + i * 256;
      __builtin_amdgcn_global_load_lds(
          (const __attribute__((address_space(1))) void*)(W + foff + ln * 4),
          (__attribute__((address_space(3))) void*)(&Wsb[buf][0][0] + foff),
          16, 0, 0);
    }
  };

  float acc[8][4];
  #pragma unroll
  for (int r = 0; r < 8; r++)
    #pragma unroll
    for (int c = 0; c < 4; c++) acc[r][c] = 0.f;
  int r0l = ty * 8;

  stage(0, 0);
  for (int c = 0; c < 8; c++) {
    int cb = c & 1;
    __syncthreads();                      // stage(c) drained; all done reading buf cb
    if (c + 1 < 8) stage(c + 1, cb ^ 1);  // flies during compute(c)
    #pragma unroll
    for (int k4 = 0; k4 < 32; k4 += 4) {
      float4 a4[8];
      #pragma unroll
      for (int r = 0; r < 8; r++)
        a4[r] = *(const float4*)&As[cb][r0l + r][k4];
      #pragma unroll
      for (int kk = 0; kk < 4; kk++) {
        float4 w4 = *(const float4*)&Wsb[cb][k4 + kk][tx * 4];
        #pragma unroll
        for (int r = 0; r < 8; r++) {
          float a = (kk == 0) ? a4[r].x : (kk == 1) ? a4[r].y
                  : (kk == 2) ? a4[r].z : a4[r].w;
          acc[r][0] = fmaf(a, w4.x, acc[r][0]);
          acc[r][1] = fmaf(a, w4.y, acc[r][1]);
          acc[r][2] = fmaf(a, w4.z, acc[r][2]);
          acc[r][3] = fmaf(a, w4.w, acc[r][3]);
        }
      }
    }
  }

  float4 b4 = *(const float4*)&bias[tx * 4];
  #pragma unroll
  for (int r = 0; r < 8; r++) {
    int row = row0 + r0l + r;
    if (row < n) {
      float4 o;
      o.x = fmaxf(acc[r][0] + b4.x, 0.f);
      o.y = fmaxf(acc[r][1] + b4.y, 0.f);
      o.z = fmaxf(acc[r][2] + b4.z, 0.f);
      o.w = fmaxf(acc[r][3] + b4.w, 0.f);
      *(float4*)&out[(size_t)row * FD + tx * 4] = o;
    }
  }
}

// ---------------- graph mean-pool: both types; 128 rows/block ----------------
__global__ __launch_bounds__(256) void k_pool(
    const float* __restrict__ x0, const float* __restrict__ x1,
    const int* __restrict__ b0, const int* __restrict__ b1,
    float* __restrict__ pool, float* __restrict__ pcnt, int n) {
  int bx = (int)blockIdx.x;
  int t = bx & 1;
  const float* x = t ? x1 : x0;
  const int* batch = t ? b1 : b0;
  float* pl = pool + t * NG * FD;
  float* pc = pcnt + t * NG;
  int tid = (int)threadIdx.x;
  int c4 = (tid & 31) * 4;
  int rs = tid >> 5;
  int start = (bx >> 1) * 128;
  int end = min(start + 128, n);
  if (start >= end) return;

  float4 acc = make_float4(0.f, 0.f, 0.f, 0.f);
  float cnt = 0.f;
  auto flush = [&](int g) {
    atomicAdd(&pl[g * FD + c4 + 0], acc.x);
    atomicAdd(&pl[g * FD + c4 + 1], acc.y);
    atomicAdd(&pl[g * FD + c4 + 2], acc.z);
    atomicAdd(&pl[g * FD + c4 + 3], acc.w);
    if ((tid & 31) == 0) atomicAdd(&pc[g], cnt);
  };

  int gfirst = batch[start];
  int glast = batch[end - 1];
  if (gfirst == glast) {
    for (int i = start + rs; i < end; i += 8) {
      float4 v = *(const float4*)&x[(size_t)i * FD + c4];
      acc.x += v.x; acc.y += v.y; acc.z += v.z; acc.w += v.w;
      cnt += 1.f;
    }
    flush(gfirst);
  } else {
    int curg = -1;
    for (int i = start + rs; i < end; i += 8) {
      int g = batch[i];
      if (g != curg) {
        if (curg >= 0) flush(curg);
        curg = g;
        acc = make_float4(0.f, 0.f, 0.f, 0.f);
        cnt = 0.f;
      }
      float4 v = *(const float4*)&x[(size_t)i * FD + c4];
      acc.x += v.x; acc.y += v.y; acc.z += v.z; acc.w += v.w;
      cnt += 1.f;
    }
    if (curg >= 0) flush(curg);
  }
}

// ---------------- head ----------------
__global__ void k_final(const float* __restrict__ pool, const float* __restrict__ pcnt,
                        const float* __restrict__ linW, const float* __restrict__ linb,
                        float* __restrict__ out) {
  int tid = (int)threadIdx.x;
  if (tid < NG * 2) {
    int g = tid >> 1, o = tid & 1;
    float s = linb[o];
    for (int t = 0; t < 2; t++) {
      float inv = 1.f / fmaxf(pcnt[t * NG + g], 1.f);
      for (int d = 0; d < FD; d++) {
        float h = pool[(t * NG + g) * FD + d] * inv;
        s = fmaf(h, linW[(t * FD + d) * 2 + o], s);
      }
    }
    out[g * 2 + o] = s;
  }
}

extern "C" void kernel_launch(void* const* d_in, const int* in_sizes, int n_in,
                              void* d_out, int out_size, void* d_ws, size_t ws_size,
                              hipStream_t stream) {
  const float* x_in[2] = {(const float*)d_in[0], (const float*)d_in[1]};
  const float* Wl   = (const float*)d_in[2];
  const float* bl   = (const float*)d_in[3];
  const float* Wr   = (const float*)d_in[4];
  const float* linW = (const float*)d_in[5];
  const float* linb = (const float*)d_in[6];
  const int* edges[2] = {(const int*)d_in[7], (const int*)d_in[8]};
  const int* batch[2] = {(const int*)d_in[9], (const int*)d_in[10]};

  const int N = in_sizes[0] / FD;    // 50000
  const int E = in_sizes[7] / 2;     // 800000

  // ---- workspace layout (512B aligned) ----
  char* p = (char*)d_ws;
  auto alloc = [&](size_t bytes) -> char* {
    char* r = p; p += (bytes + 511) & ~(size_t)511; return r;
  };
  int* deg[2];  deg[0]  = (int*)alloc((size_t)N * 4); deg[1]  = (int*)alloc((size_t)N * 4);
  float* pool  = (float*)alloc(2 * NG * FD * 4);
  float* pcnt  = (float*)alloc(2 * NG * 4);
  size_t zero_bytes = (size_t)(p - (char*)d_ws);       // deg+pool+pcnt need zeroing
  int* off[2];  off[0]  = (int*)alloc((size_t)N * 4); off[1]  = (int*)alloc((size_t)N * 4);
  int* wptr[2]; wptr[0] = (int*)alloc((size_t)N * 4); wptr[1] = (int*)alloc((size_t)N * 4);
  int* csr[2];  csr[0]  = (int*)alloc((size_t)E * 4); csr[1]  = (int*)alloc((size_t)E * 4);
  float* meanb[2]; meanb[0] = (float*)alloc((size_t)N * FD * 4);
                   meanb[1] = (float*)alloc((size_t)N * FD * 4);
  float* xbuf[2][2];
  for (int t = 0; t < 2; t++)
    for (int b = 0; b < 2; b++) xbuf[t][b] = (float*)alloc((size_t)N * FD * 4);
  if ((size_t)(p - (char*)d_ws) > ws_size) return;     // insufficient workspace

  hipMemsetAsync(d_ws, 0, zero_bytes, stream);

  int eb2 = (2 * E + 255) / 256;
  k_count_deg<<<eb2, 256, 0, stream>>>(edges[0], edges[1], deg[0], deg[1], E);
  k_scan<<<2, 1024, 0, stream>>>(deg[0], deg[1], off[0], off[1], wptr[0], wptr[1], N);
  k_fill_csr<<<eb2, 256, 0, stream>>>(edges[0], edges[1], wptr[0], wptr[1], csr[0], csr[1], E);

  int gblocks = 2 * ((N + 63) / 64);
  int ablocks = 2 * ((N + 7) / 8);
  const float* cur[2] = {x_in[0], x_in[1]};
  int pp = 0;
  for (int l = 0; l < NL; l++) {
    float* nxt0 = xbuf[0][pp];
    float* nxt1 = xbuf[1][pp];
    k_agg<<<ablocks, 256, 0, stream>>>(cur[0], cur[1], csr[0], csr[1],
                                       off[0], off[1], deg[0], deg[1],
                                       meanb[0], meanb[1], N);
    k_gemm<<<gblocks, 256, 0, stream>>>(meanb[0], meanb[1], cur[0], cur[1],
                                        Wl + (size_t)l * 2 * FD * FD,
                                        Wr + (size_t)l * 2 * FD * FD,
                                        bl + (size_t)l * 2 * FD,
                                        nxt0, nxt1, N);
    cur[0] = nxt0; cur[1] = nxt1;
    pp ^= 1;
  }

  int pblocks = 2 * ((N + 127) / 128);
  k_pool<<<pblocks, 256, 0, stream>>>(cur[0], cur[1], batch[0], batch[1], pool, pcnt, N);
  k_final<<<1, 64, 0, stream>>>(pool, pcnt, linW, linb, (float*)d_out);
}

// Round 5
// 815.987 us; speedup vs baseline: 22.7801x; 1.5055x over previous
//
#include <hip/hip_runtime.h>
#include <hip/hip_bf16.h>
#include <cstdint>
#include <cstddef>

static constexpr int FD = 128;   // feature dim
static constexpr int NG = 16;    // graphs per batch
static constexpr int NL = 3;     // layers

typedef __attribute__((ext_vector_type(8))) short short8;
typedef __attribute__((ext_vector_type(4))) float floatx4;

__device__ __forceinline__ short f2bf(float v) {
  union { __hip_bfloat16 b; short s; } u;
  u.b = __float2bfloat16(v);
  return u.s;
}

// ---------------- CSR build (both types per launch) ----------------
__global__ void k_count_deg(const int* __restrict__ e0, const int* __restrict__ e1,
                            int* __restrict__ d0, int* __restrict__ d1, int E) {
  int i = blockIdx.x * blockDim.x + threadIdx.x;
  if (i < E) atomicAdd(&d0[e0[E + i]], 1);
  else if (i < 2 * E) atomicAdd(&d1[e1[E + (i - E)]], 1);
}

__global__ __launch_bounds__(1024) void k_scan(
    const int* __restrict__ dg0, const int* __restrict__ dg1,
    int* __restrict__ of0, int* __restrict__ of1,
    int* __restrict__ wp0, int* __restrict__ wp1, int n) {
  const int* deg = blockIdx.x ? dg1 : dg0;
  int* off = blockIdx.x ? of1 : of0;
  int* wptr = blockIdx.x ? wp1 : wp0;
  __shared__ int wsum[16];
  __shared__ int carry_s;
  int tid = (int)threadIdx.x;
  int lane = tid & 63;
  int wave = tid >> 6;
  if (tid == 0) carry_s = 0;
  __syncthreads();
  for (int base = 0; base < n; base += 4096) {
    int i0 = base + tid * 4;
    int v[4];
    int s = 0;
    #pragma unroll
    for (int j = 0; j < 4; j++) { v[j] = (i0 + j < n) ? deg[i0 + j] : 0; s += v[j]; }
    int sc = s;
    #pragma unroll
    for (int d = 1; d < 64; d <<= 1) {
      int t = __shfl_up(sc, d, 64);
      if (lane >= d) sc += t;
    }
    if (lane == 63) wsum[wave] = sc;
    __syncthreads();
    if (wave == 0 && lane < 16) {
      int ws = wsum[lane];
      int wsc = ws;
      #pragma unroll
      for (int d = 1; d < 16; d <<= 1) {
        int t = __shfl_up(wsc, d, 64);
        if (lane >= d) wsc += t;
      }
      wsum[lane] = wsc - ws;
    }
    __syncthreads();
    int excl = carry_s + wsum[wave] + (sc - s);
    #pragma unroll
    for (int j = 0; j < 4; j++) {
      if (i0 + j < n) { off[i0 + j] = excl; wptr[i0 + j] = excl; }
      excl += v[j];
    }
    __syncthreads();
    if (tid == 1023) carry_s += wsum[15] + sc;
    __syncthreads();
  }
}

__global__ void k_fill_csr(const int* __restrict__ e0, const int* __restrict__ e1,
                           int* __restrict__ w0, int* __restrict__ w1,
                           int* __restrict__ c0, int* __restrict__ c1, int E) {
  int i = blockIdx.x * blockDim.x + threadIdx.x;
  if (i < E) {
    int pos = atomicAdd(&w0[e0[E + i]], 1);
    c0[pos] = e0[i];
  } else if (i < 2 * E) {
    int j = i - E;
    int pos = atomicAdd(&w1[e1[E + j]], 1);
    c1[pos] = e1[j];
  }
}

// ---------------- W -> fragment-layout bf16 hi/lo ----------------
// Wf layout per (layer,type) combo (stride 65536 shorts = 128KB):
//   short offset = ks*8192 + h*4096 + nt*512 + lane*8 + j
//   element: k = ks*32 + (lane>>4)*8 + j (0..255: <128 -> Wl, else Wr), n = nt*16 + (lane&15)
__global__ void k_wconv(const float* __restrict__ Wl, const float* __restrict__ Wr,
                        short* __restrict__ Wf) {
  int u = blockIdx.x * blockDim.x + threadIdx.x;
  if (u >= 6 * 8192) return;
  int combo = u >> 13;
  int r = u & 8191;
  int l  = r & 63;
  int nt = (r >> 6) & 7;
  int h  = (r >> 9) & 1;
  int ks = r >> 10;
  short8 s;
  #pragma unroll
  for (int j = 0; j < 8; j++) {
    int k = ks * 32 + (l >> 4) * 8 + j;
    int n = nt * 16 + (l & 15);
    float w = (k < FD) ? Wl[((size_t)combo * FD + k) * FD + n]
                       : Wr[((size_t)combo * FD + (k - FD)) * FD + n];
    __hip_bfloat16 hb = __float2bfloat16(w);
    if (h == 0) {
      union { __hip_bfloat16 b; short t; } uu; uu.b = hb; s[j] = uu.t;
    } else {
      float hf = __bfloat162float(hb);
      s[j] = f2bf(w - hf);
    }
  }
  *(short8*)(Wf + (size_t)combo * 65536 + (size_t)r * 8) = s;
}

// ---------------- x (fp32 row-major) -> A-fragment bf16 layout ----------------
// AF layout: short offset = g*2048 + kb*128 + m*8 + j   (node = g*16+m, feat = kb*8+j)
__global__ __launch_bounds__(256) void k_xconv(
    const float* __restrict__ x0, const float* __restrict__ x1,
    short* __restrict__ a0, short* __restrict__ a1, int n) {
  int bx = blockIdx.x;
  int t = bx & 1;
  int g = bx >> 1;
  const float* x = t ? x1 : x0;
  short* a = t ? a1 : a0;
  int tid = (int)threadIdx.x;
  int m = tid & 15;
  int kb = tid >> 4;          // 0..15
  int node = g * 16 + m;
  if (node >= n) return;
  const float* src = x + (size_t)node * FD + kb * 8;
  short8 s;
  #pragma unroll
  for (int j = 0; j < 8; j++) s[j] = f2bf(src[j]);
  *(short8*)(a + (size_t)g * 2048 + kb * 128 + m * 8) = s;
}

// ---------------- neighbor mean -> AF bf16 (16 nodes/block, 512 threads) ----------------
__global__ __launch_bounds__(512) void k_agg(
    const float* __restrict__ x0, const float* __restrict__ x1,
    const int* __restrict__ csr0, const int* __restrict__ csr1,
    const int* __restrict__ off0, const int* __restrict__ off1,
    const int* __restrict__ deg0, const int* __restrict__ deg1,
    short* __restrict__ m0, short* __restrict__ m1, int n)
{
  __shared__ float M[16][132];
  int bx = blockIdx.x;
  int t = bx & 1;
  int g = bx >> 1;
  const float* x  = t ? x1 : x0;
  const int* csr  = t ? csr1 : csr0;
  const int* off  = t ? off1 : off0;
  const int* deg  = t ? deg1 : deg0;
  short* mAF      = t ? m1 : m0;
  int tid = (int)threadIdx.x;
  int s = tid >> 5;             // node slot 0..15
  int tx = tid & 31;
  int c4 = tx * 4;
  int node = g * 16 + s;
  if (node < n) {
    int o = off[node], d = deg[node];
    float4 acc = make_float4(0.f, 0.f, 0.f, 0.f);
    for (int k0 = 0; k0 < d; k0 += 32) {
      int idx = (k0 + tx < d) ? csr[o + k0 + tx] : 0;
      int mm = min(32, d - k0);
      int j = 0;
      for (; j + 8 <= mm; j += 8) {
        int s0 = __shfl(idx, j + 0, 32);
        int s1 = __shfl(idx, j + 1, 32);
        int s2 = __shfl(idx, j + 2, 32);
        int s3 = __shfl(idx, j + 3, 32);
        int s4 = __shfl(idx, j + 4, 32);
        int s5 = __shfl(idx, j + 5, 32);
        int s6 = __shfl(idx, j + 6, 32);
        int s7 = __shfl(idx, j + 7, 32);
        float4 v0 = *(const float4*)&x[(size_t)s0 * FD + c4];
        float4 v1 = *(const float4*)&x[(size_t)s1 * FD + c4];
        float4 v2 = *(const float4*)&x[(size_t)s2 * FD + c4];
        float4 v3 = *(const float4*)&x[(size_t)s3 * FD + c4];
        float4 v4 = *(const float4*)&x[(size_t)s4 * FD + c4];
        float4 v5 = *(const float4*)&x[(size_t)s5 * FD + c4];
        float4 v6 = *(const float4*)&x[(size_t)s6 * FD + c4];
        float4 v7 = *(const float4*)&x[(size_t)s7 * FD + c4];
        acc.x += ((v0.x + v1.x) + (v2.x + v3.x)) + ((v4.x + v5.x) + (v6.x + v7.x));
        acc.y += ((v0.y + v1.y) + (v2.y + v3.y)) + ((v4.y + v5.y) + (v6.y + v7.y));
        acc.z += ((v0.z + v1.z) + (v2.z + v3.z)) + ((v4.z + v5.z) + (v6.z + v7.z));
        acc.w += ((v0.w + v1.w) + (v2.w + v3.w)) + ((v4.w + v5.w) + (v6.w + v7.w));
      }
      for (; j < mm; j++) {
        int si = __shfl(idx, j, 32);
        float4 v = *(const float4*)&x[(size_t)si * FD + c4];
        acc.x += v.x; acc.y += v.y; acc.z += v.z; acc.w += v.w;
      }
    }
    float inv = 1.f / fmaxf((float)d, 1.f);
    M[s][c4 + 0] = acc.x * inv;
    M[s][c4 + 1] = acc.y * inv;
    M[s][c4 + 2] = acc.z * inv;
    M[s][c4 + 3] = acc.w * inv;
  }
  __syncthreads();
  if (tid < 256) {
    int m = tid & 15;
    int kb = tid >> 4;          // 0..15
    if (g * 16 + m < n) {
      short8 v;
      #pragma unroll
      for (int j = 0; j < 8; j++) v[j] = f2bf(M[m][kb * 8 + j]);
      *(short8*)(mAF + (size_t)g * 2048 + kb * 128 + m * 8) = v;
    }
  }
}

// ---------------- MFMA GEMM: y = relu([mean|x] @ [Wl;Wr] + b) ----------------
// A = bf16 AF frags (hi only, per-node rounding is pool-averaged out).
// W = bf16 hi+lo frags (2 mfma passes preserve W to ~2^-17).
// 128x128 tile, 4 waves (each 64x64 quadrant), W kstep-slice dbuf in LDS.
__global__ __launch_bounds__(256) void k_gemm(
    const short* __restrict__ mAF0, const short* __restrict__ mAF1,
    const short* __restrict__ xAF0, const short* __restrict__ xAF1,
    const short* __restrict__ Wf,       // layer base: [2 types][65536]
    const float* __restrict__ bl,       // layer base: [2 types][128]
    float* __restrict__ out0, float* __restrict__ out1,
    short* __restrict__ oAF0, short* __restrict__ oAF1, int n)
{
  __shared__ __align__(16) char smem[32768];
  short* WfL = (short*)smem;            // [2][8192] dbuf during K-loop
  float* S   = (float*)smem;            // [128][64] epilogue scratch (after loop)

  int tid = (int)threadIdx.x;
  int l = tid & 63;
  int wv = tid >> 6;
  int bx = (int)blockIdx.x;
  int t = bx & 1;
  int tile = bx >> 1;
  int row0 = tile * 128;
  int g0 = tile * 8;

  const short* mAF = t ? mAF1 : mAF0;
  const short* xAF = t ? xAF1 : xAF0;
  const short* Wc  = Wf + (size_t)t * 65536;
  const float* bias = bl + t * FD;
  float* out = t ? out1 : out0;
  short* oAF = t ? oAF1 : oAF0;

  int rhalf = wv & 1;
  int chalf = wv >> 1;
  int laneoff = (l >> 4) * 128 + (l & 15) * 8;

  auto stageW = [&](int ks, int buf) {
    const short* src = Wc + ks * 8192 + wv * 2048;
    short* dst = WfL + buf * 8192 + wv * 2048;
    #pragma unroll
    for (int i = 0; i < 4; i++) {
      __builtin_amdgcn_global_load_lds(
          (const __attribute__((address_space(1))) void*)(src + i * 512 + l * 8),
          (__attribute__((address_space(3))) void*)(dst + i * 512),
          16, 0, 0);
    }
  };

  floatx4 acc[4][4];
  #pragma unroll
  for (int i = 0; i < 4; i++)
    #pragma unroll
    for (int q = 0; q < 4; q++) acc[i][q] = (floatx4)0.f;

  short8 Acur[4], Anext[4];
  auto loadA = [&](int ks, short8* A) {
    const short* Ab = (ks < 4 ? mAF : xAF) + (ks & 3) * 512;
    #pragma unroll
    for (int i = 0; i < 4; i++) {
      int g = g0 + rhalf * 4 + i;
      A[i] = *(const short8*)(Ab + (size_t)g * 2048 + laneoff);
    }
  };

  stageW(0, 0);
  loadA(0, Acur);
  for (int ks = 0; ks < 8; ks++) {
    int buf = ks & 1;
    __syncthreads();                       // drains stage(ks); readers of buf^1 done
    if (ks < 7) { stageW(ks + 1, buf ^ 1); loadA(ks + 1, Anext); }
    const short* WB = WfL + buf * 8192;
    #pragma unroll
    for (int q = 0; q < 4; q++) {
      int nt = chalf * 4 + q;
      short8 whi = *(const short8*)(WB + nt * 512 + l * 8);
      short8 wlo = *(const short8*)(WB + 4096 + nt * 512 + l * 8);
      #pragma unroll
      for (int i = 0; i < 4; i++) {
        acc[i][q] = __builtin_amdgcn_mfma_f32_16x16x32_bf16(Acur[i], whi, acc[i][q], 0, 0, 0);
        acc[i][q] = __builtin_amdgcn_mfma_f32_16x16x32_bf16(Acur[i], wlo, acc[i][q], 0, 0, 0);
      }
    }
    #pragma unroll
    for (int i = 0; i < 4; i++) Acur[i] = Anext[i];
  }

  // epilogue: bias + relu, fp32 row-major store
  int colbase = chalf * 64;
  #pragma unroll
  for (int i = 0; i < 4; i++) {
    #pragma unroll
    for (int q = 0; q < 4; q++) {
      int col = colbase + q * 16 + (l & 15);
      float b = bias[col];
      #pragma unroll
      for (int r = 0; r < 4; r++) {
        int row = row0 + rhalf * 64 + i * 16 + (l >> 4) * 4 + r;
        float v = fmaxf(acc[i][q][r] + b, 0.f);
        acc[i][q][r] = v;
        if (row < n) out[(size_t)row * FD + col] = v;
      }
    }
  }

  // AF-bf16 emit via LDS transpose, one 64-col half at a time
  #pragma unroll
  for (int ph = 0; ph < 2; ph++) {
    __syncthreads();
    if (chalf == ph) {
      #pragma unroll
      for (int i = 0; i < 4; i++)
        #pragma unroll
        for (int q = 0; q < 4; q++)
          #pragma unroll
          for (int r = 0; r < 4; r++)
            S[(rhalf * 64 + i * 16 + (l >> 4) * 4 + r) * 64 + q * 16 + (l & 15)] = acc[i][q][r];
    }
    __syncthreads();
    #pragma unroll
    for (int it = 0; it < 4; it++) {
      int u = it * 256 + tid;
      int m = u & 15;
      int kb = (u >> 4) & 7;
      int grp = u >> 7;                    // 0..7
      int g = g0 + grp;
      if (row0 + grp * 16 + m < n) {
        short8 s;
        #pragma unroll
        for (int j = 0; j < 8; j++) s[j] = f2bf(S[(grp * 16 + m) * 64 + kb * 8 + j]);
        *(short8*)(oAF + (size_t)g * 2048 + (ph * 8 + kb) * 128 + m * 8) = s;
      }
    }
  }
}

// ---------------- graph mean-pool (fp32 row-major input) ----------------
__global__ __launch_bounds__(256) void k_pool(
    const float* __restrict__ x0, const float* __restrict__ x1,
    const int* __restrict__ b0, const int* __restrict__ b1,
    float* __restrict__ pool, float* __restrict__ pcnt, int n) {
  int bx = (int)blockIdx.x;
  int t = bx & 1;
  const float* x = t ? x1 : x0;
  const int* batch = t ? b1 : b0;
  float* pl = pool + t * NG * FD;
  float* pc = pcnt + t * NG;
  int tid = (int)threadIdx.x;
  int c4 = (tid & 31) * 4;
  int rs = tid >> 5;
  int start = (bx >> 1) * 128;
  int end = min(start + 128, n);
  if (start >= end) return;

  float4 acc = make_float4(0.f, 0.f, 0.f, 0.f);
  float cnt = 0.f;
  auto flush = [&](int g) {
    atomicAdd(&pl[g * FD + c4 + 0], acc.x);
    atomicAdd(&pl[g * FD + c4 + 1], acc.y);
    atomicAdd(&pl[g * FD + c4 + 2], acc.z);
    atomicAdd(&pl[g * FD + c4 + 3], acc.w);
    if ((tid & 31) == 0) atomicAdd(&pc[g], cnt);
  };

  int gfirst = batch[start];
  int glast = batch[end - 1];
  if (gfirst == glast) {
    for (int i = start + rs; i < end; i += 8) {
      float4 v = *(const float4*)&x[(size_t)i * FD + c4];
      acc.x += v.x; acc.y += v.y; acc.z += v.z; acc.w += v.w;
      cnt += 1.f;
    }
    flush(gfirst);
  } else {
    int curg = -1;
    for (int i = start + rs; i < end; i += 8) {
      int g = batch[i];
      if (g != curg) {
        if (curg >= 0) flush(curg);
        curg = g;
        acc = make_float4(0.f, 0.f, 0.f, 0.f);
        cnt = 0.f;
      }
      float4 v = *(const float4*)&x[(size_t)i * FD + c4];
      acc.x += v.x; acc.y += v.y; acc.z += v.z; acc.w += v.w;
      cnt += 1.f;
    }
    if (curg >= 0) flush(curg);
  }
}

// ---------------- head ----------------
__global__ void k_final(const float* __restrict__ pool, const float* __restrict__ pcnt,
                        const float* __restrict__ linW, const float* __restrict__ linb,
                        float* __restrict__ out) {
  int tid = (int)threadIdx.x;
  if (tid < NG * 2) {
    int g = tid >> 1, o = tid & 1;
    float s = linb[o];
    for (int t = 0; t < 2; t++) {
      float inv = 1.f / fmaxf(pcnt[t * NG + g], 1.f);
      for (int d = 0; d < FD; d++) {
        float h = pool[(t * NG + g) * FD + d] * inv;
        s = fmaf(h, linW[(t * FD + d) * 2 + o], s);
      }
    }
    out[g * 2 + o] = s;
  }
}

extern "C" void kernel_launch(void* const* d_in, const int* in_sizes, int n_in,
                              void* d_out, int out_size, void* d_ws, size_t ws_size,
                              hipStream_t stream) {
  const float* x_in[2] = {(const float*)d_in[0], (const float*)d_in[1]};
  const float* Wl   = (const float*)d_in[2];
  const float* bl   = (const float*)d_in[3];
  const float* Wr   = (const float*)d_in[4];
  const float* linW = (const float*)d_in[5];
  const float* linb = (const float*)d_in[6];
  const int* edges[2] = {(const int*)d_in[7], (const int*)d_in[8]};
  const int* batch[2] = {(const int*)d_in[9], (const int*)d_in[10]};

  const int N = in_sizes[0] / FD;    // 50000
  const int E = in_sizes[7] / 2;     // 800000
  const int NGRP = (N + 15) / 16;    // 3125
  const int NTILE = (N + 127) / 128; // 391
  const size_t AFG = (size_t)(NTILE * 8 + 8) * 2048; // AF shorts (padded past last tile)

  // ---- workspace layout (512B aligned) ----
  char* p = (char*)d_ws;
  auto alloc = [&](size_t bytes) -> char* {
    char* r = p; p += (bytes + 511) & ~(size_t)511; return r;
  };
  int* deg[2];  deg[0]  = (int*)alloc((size_t)N * 4); deg[1]  = (int*)alloc((size_t)N * 4);
  float* pool  = (float*)alloc(2 * NG * FD * 4);
  float* pcnt  = (float*)alloc(2 * NG * 4);
  size_t zero_bytes = (size_t)(p - (char*)d_ws);       // deg+pool+pcnt need zeroing
  int* off[2];  off[0]  = (int*)alloc((size_t)N * 4); off[1]  = (int*)alloc((size_t)N * 4);
  int* wptr[2]; wptr[0] = (int*)alloc((size_t)N * 4); wptr[1] = (int*)alloc((size_t)N * 4);
  int* csr[2];  csr[0]  = (int*)alloc((size_t)E * 4); csr[1]  = (int*)alloc((size_t)E * 4);
  short* Wf    = (short*)alloc((size_t)6 * 65536 * 2);
  short* mAF[2]; mAF[0] = (short*)alloc(AFG * 2); mAF[1] = (short*)alloc(AFG * 2);
  short* xAF[2][2];
  for (int t = 0; t < 2; t++)
    for (int b = 0; b < 2; b++) xAF[t][b] = (short*)alloc(AFG * 2);
  float* xbuf[2][2];
  for (int t = 0; t < 2; t++)
    for (int b = 0; b < 2; b++) xbuf[t][b] = (float*)alloc((size_t)N * FD * 4);
  if ((size_t)(p - (char*)d_ws) > ws_size) return;     // insufficient workspace

  hipMemsetAsync(d_ws, 0, zero_bytes, stream);

  // weight + input conversion
  k_wconv<<<(6 * 8192 + 255) / 256, 256, 0, stream>>>(Wl, Wr, Wf);
  k_xconv<<<2 * NGRP, 256, 0, stream>>>(x_in[0], x_in[1], xAF[0][0], xAF[1][0], N);

  int eb2 = (2 * E + 255) / 256;
  k_count_deg<<<eb2, 256, 0, stream>>>(edges[0], edges[1], deg[0], deg[1], E);
  k_scan<<<2, 1024, 0, stream>>>(deg[0], deg[1], off[0], off[1], wptr[0], wptr[1], N);
  k_fill_csr<<<eb2, 256, 0, stream>>>(edges[0], edges[1], wptr[0], wptr[1], csr[0], csr[1], E);

  const float* cur[2] = {x_in[0], x_in[1]};
  int pp = 0;
  for (int l = 0; l < NL; l++) {
    float* nxt0 = xbuf[0][pp ^ 1 & 1];  // ping-pong fp32
    float* nxt1 = xbuf[1][pp ^ 1 & 1];
    nxt0 = xbuf[0][(l & 1) ^ 1]; nxt1 = xbuf[1][(l & 1) ^ 1];
    k_agg<<<2 * NGRP, 512, 0, stream>>>(cur[0], cur[1], csr[0], csr[1],
                                        off[0], off[1], deg[0], deg[1],
                                        mAF[0], mAF[1], N);
    k_gemm<<<2 * NTILE, 256, 0, stream>>>(
        mAF[0], mAF[1], xAF[0][pp], xAF[1][pp],
        Wf + (size_t)l * 2 * 65536, bl + (size_t)l * 2 * FD,
        nxt0, nxt1, xAF[0][pp ^ 1], xAF[1][pp ^ 1], N);
    cur[0] = nxt0; cur[1] = nxt1;
    pp ^= 1;
  }

  int pblocks = 2 * ((N + 127) / 128);
  k_pool<<<pblocks, 256, 0, stream>>>(cur[0], cur[1], batch[0], batch[1], pool, pcnt, N);
  k_final<<<1, 64, 0, stream>>>(pool, pcnt, linW, linb, (float*)d_out);
}

// Round 6
// 467.769 us; speedup vs baseline: 39.7382x; 1.7444x over previous
//
#include <hip/hip_runtime.h>
#include <hip/hip_bf16.h>
#include <cstdint>
#include <cstddef>

static constexpr int FD = 128;   // feature dim
static constexpr int NG = 16;    // graphs per batch
static constexpr int NL = 3;     // layers

typedef __attribute__((ext_vector_type(8))) short short8;
typedef __attribute__((ext_vector_type(4))) float floatx4;

__device__ __forceinline__ short f2bf(float v) {
  union { __hip_bfloat16 b; short s; } u;
  u.b = __float2bfloat16(v);
  return u.s;
}
__device__ __forceinline__ float bfu(unsigned short u) {
  return __uint_as_float((unsigned int)u << 16);
}

// ---------------- pass A: bucket edges by dst>>8, LDS-sorted staging ----------------
// entry = src | (dst<<16)  (requires N <= 65536)
__global__ __launch_bounds__(256) void k_bucket(
    const int* __restrict__ e0, const int* __restrict__ e1,
    int* __restrict__ gcount, int* __restrict__ buckets,
    int E, int NBUCK, int CAP)
{
  __shared__ int hist[256], lexcl[256], gbase[256], wcur[256];
  __shared__ int staged[4096];
  __shared__ int wsum[4];
  __shared__ int totalS;
  int tid = (int)threadIdx.x;
  int bx = (int)blockIdx.x;
  int t = bx & 1;
  int chunk = (bx >> 1) * 4096;
  const int* eg = t ? e1 : e0;
  hist[tid] = 0;
  __syncthreads();
  unsigned int ent[16];
  #pragma unroll
  for (int k = 0; k < 16; k++) {
    int i = chunk + k * 256 + tid;
    if (i < E) {
      unsigned int src = (unsigned int)eg[i];
      unsigned int dst = (unsigned int)eg[E + i];
      ent[k] = src | (dst << 16);
      atomicAdd(&hist[dst >> 8], 1);
    } else ent[k] = 0xFFFFFFFFu;
  }
  __syncthreads();
  // block scan of hist[256]
  int lane = tid & 63, wv = tid >> 6;
  int v = hist[tid];
  int sc = v;
  #pragma unroll
  for (int d = 1; d < 64; d <<= 1) {
    int tt = __shfl_up(sc, d, 64);
    if (lane >= d) sc += tt;
  }
  if (lane == 63) wsum[wv] = sc;
  __syncthreads();
  int wpre = 0;
  for (int w = 0; w < wv; w++) wpre += wsum[w];
  int excl = wpre + sc - v;
  lexcl[tid] = excl;
  wcur[tid] = excl;
  gbase[tid] = v ? atomicAdd(&gcount[t * 256 + tid], v) : 0;
  if (tid == 255) totalS = excl + v;
  __syncthreads();
  #pragma unroll
  for (int k = 0; k < 16; k++) {
    if (ent[k] != 0xFFFFFFFFu) {
      int b = ent[k] >> 24;
      int pos = atomicAdd(&wcur[b], 1);
      staged[pos] = (int)ent[k];
    }
  }
  __syncthreads();
  int total = totalS;
  for (int j = tid; j < total; j += 256) {
    unsigned int e = (unsigned int)staged[j];
    int b = e >> 24;
    int gp = gbase[b] + (j - lexcl[b]);
    if (gp < CAP) buckets[((size_t)t * NBUCK + b) * CAP + gp] = (int)e;
  }
}

// ---------------- pass B: per-bucket deg/off/csr with LDS atomics only ----------------
__global__ __launch_bounds__(256) void k_csr(
    const int* __restrict__ gcount, const int* __restrict__ buckets,
    int* __restrict__ csr0, int* __restrict__ csr1,
    int* __restrict__ off0, int* __restrict__ off1,
    int* __restrict__ deg0, int* __restrict__ deg1,
    int NBUCK, int CAP, int n)
{
  __shared__ int hist[256], wcur[256], wsum[4];
  int tid = (int)threadIdx.x;
  int bx = (int)blockIdx.x;
  int t = bx & 1;
  int b = bx >> 1;
  int cnt = gcount[t * 256 + b];
  if (cnt > CAP) cnt = CAP;
  const int* base = buckets + ((size_t)t * NBUCK + b) * CAP;
  int* csr = t ? csr1 : csr0;
  int* off = t ? off1 : off0;
  int* deg = t ? deg1 : deg0;
  hist[tid] = 0;
  __syncthreads();
  for (int j = tid; j < cnt; j += 256)
    atomicAdd(&hist[((unsigned int)base[j] >> 16) & 255], 1);
  __syncthreads();
  int lane = tid & 63, wv = tid >> 6;
  int v = hist[tid];
  int sc = v;
  #pragma unroll
  for (int d = 1; d < 64; d <<= 1) {
    int tt = __shfl_up(sc, d, 64);
    if (lane >= d) sc += tt;
  }
  if (lane == 63) wsum[wv] = sc;
  __syncthreads();
  int wpre = 0;
  for (int w = 0; w < wv; w++) wpre += wsum[w];
  int excl = wpre + sc - v;
  wcur[tid] = excl;
  int node = b * 256 + tid;
  if (node < n) { deg[node] = v; off[node] = b * CAP + excl; }
  __syncthreads();
  for (int j = tid; j < cnt; j += 256) {
    unsigned int e = (unsigned int)base[j];
    int ld = (e >> 16) & 255;
    int pos = atomicAdd(&wcur[ld], 1);
    csr[b * CAP + pos] = (int)(e & 0xFFFFu);
  }
}

// ---------------- W -> fragment-layout bf16 hi/lo ----------------
__global__ void k_wconv(const float* __restrict__ Wl, const float* __restrict__ Wr,
                        short* __restrict__ Wf) {
  int u = blockIdx.x * blockDim.x + threadIdx.x;
  if (u >= 6 * 8192) return;
  int combo = u >> 13;
  int r = u & 8191;
  int l  = r & 63;
  int nt = (r >> 6) & 7;
  int h  = (r >> 9) & 1;
  int ks = r >> 10;
  short8 s;
  #pragma unroll
  for (int j = 0; j < 8; j++) {
    int k = ks * 32 + (l >> 4) * 8 + j;
    int n = nt * 16 + (l & 15);
    float w = (k < FD) ? Wl[((size_t)combo * FD + k) * FD + n]
                       : Wr[((size_t)combo * FD + (k - FD)) * FD + n];
    __hip_bfloat16 hb = __float2bfloat16(w);
    if (h == 0) {
      union { __hip_bfloat16 b; short t; } uu; uu.b = hb; s[j] = uu.t;
    } else {
      float hf = __bfloat162float(hb);
      s[j] = f2bf(w - hf);
    }
  }
  *(short8*)(Wf + (size_t)combo * 65536 + (size_t)r * 8) = s;
}

// ---------------- x (fp32) -> AF bf16 + row-major bf16 ----------------
__global__ __launch_bounds__(256) void k_xconv(
    const float* __restrict__ x0, const float* __restrict__ x1,
    short* __restrict__ a0, short* __restrict__ a1,
    short* __restrict__ r0, short* __restrict__ r1, int n) {
  int bx = blockIdx.x;
  int t = bx & 1;
  int g = bx >> 1;
  const float* x = t ? x1 : x0;
  short* a = t ? a1 : a0;
  short* rm = t ? r1 : r0;
  int tid = (int)threadIdx.x;
  int m = tid & 15;
  int kb = tid >> 4;          // 0..15
  int node = g * 16 + m;
  if (node >= n) return;
  const float* src = x + (size_t)node * FD + kb * 8;
  short8 s;
  #pragma unroll
  for (int j = 0; j < 8; j++) s[j] = f2bf(src[j]);
  *(short8*)(a + (size_t)g * 2048 + kb * 128 + m * 8) = s;
  *(short8*)(rm + (size_t)node * FD + kb * 8) = s;
}

// ---------------- neighbor mean from bf16 rows -> AF bf16 ----------------
__global__ __launch_bounds__(512) void k_agg(
    const unsigned short* __restrict__ x0, const unsigned short* __restrict__ x1,
    const int* __restrict__ csr0, const int* __restrict__ csr1,
    const int* __restrict__ off0, const int* __restrict__ off1,
    const int* __restrict__ deg0, const int* __restrict__ deg1,
    short* __restrict__ m0, short* __restrict__ m1, int n)
{
  __shared__ float M[16][132];
  int bx = blockIdx.x;
  int t = bx & 1;
  int g = bx >> 1;
  const unsigned short* x = t ? x1 : x0;
  const int* csr  = t ? csr1 : csr0;
  const int* off  = t ? off1 : off0;
  const int* deg  = t ? deg1 : deg0;
  short* mAF      = t ? m1 : m0;
  int tid = (int)threadIdx.x;
  int s = tid >> 5;             // node slot 0..15
  int tx = tid & 31;
  int c4 = tx * 4;
  int node = g * 16 + s;
  if (node < n) {
    int o = off[node], d = deg[node];
    float a0 = 0.f, a1 = 0.f, a2 = 0.f, a3 = 0.f;
    for (int k0 = 0; k0 < d; k0 += 32) {
      int idx = (k0 + tx < d) ? csr[o + k0 + tx] : 0;
      int mm = min(32, d - k0);
      int j = 0;
      for (; j + 8 <= mm; j += 8) {
        int s0 = __shfl(idx, j + 0, 32);
        int s1 = __shfl(idx, j + 1, 32);
        int s2 = __shfl(idx, j + 2, 32);
        int s3 = __shfl(idx, j + 3, 32);
        int s4 = __shfl(idx, j + 4, 32);
        int s5 = __shfl(idx, j + 5, 32);
        int s6 = __shfl(idx, j + 6, 32);
        int s7 = __shfl(idx, j + 7, 32);
        ushort4 u0 = *(const ushort4*)&x[(size_t)s0 * FD + c4];
        ushort4 u1 = *(const ushort4*)&x[(size_t)s1 * FD + c4];
        ushort4 u2 = *(const ushort4*)&x[(size_t)s2 * FD + c4];
        ushort4 u3 = *(const ushort4*)&x[(size_t)s3 * FD + c4];
        ushort4 u4 = *(const ushort4*)&x[(size_t)s4 * FD + c4];
        ushort4 u5 = *(const ushort4*)&x[(size_t)s5 * FD + c4];
        ushort4 u6 = *(const ushort4*)&x[(size_t)s6 * FD + c4];
        ushort4 u7 = *(const ushort4*)&x[(size_t)s7 * FD + c4];
        a0 += ((bfu(u0.x) + bfu(u1.x)) + (bfu(u2.x) + bfu(u3.x)))
            + ((bfu(u4.x) + bfu(u5.x)) + (bfu(u6.x) + bfu(u7.x)));
        a1 += ((bfu(u0.y) + bfu(u1.y)) + (bfu(u2.y) + bfu(u3.y)))
            + ((bfu(u4.y) + bfu(u5.y)) + (bfu(u6.y) + bfu(u7.y)));
        a2 += ((bfu(u0.z) + bfu(u1.z)) + (bfu(u2.z) + bfu(u3.z)))
            + ((bfu(u4.z) + bfu(u5.z)) + (bfu(u6.z) + bfu(u7.z)));
        a3 += ((bfu(u0.w) + bfu(u1.w)) + (bfu(u2.w) + bfu(u3.w)))
            + ((bfu(u4.w) + bfu(u5.w)) + (bfu(u6.w) + bfu(u7.w)));
      }
      for (; j < mm; j++) {
        int si = __shfl(idx, j, 32);
        ushort4 u = *(const ushort4*)&x[(size_t)si * FD + c4];
        a0 += bfu(u.x); a1 += bfu(u.y); a2 += bfu(u.z); a3 += bfu(u.w);
      }
    }
    float inv = 1.f / fmaxf((float)d, 1.f);
    M[s][c4 + 0] = a0 * inv;
    M[s][c4 + 1] = a1 * inv;
    M[s][c4 + 2] = a2 * inv;
    M[s][c4 + 3] = a3 * inv;
  }
  __syncthreads();
  if (tid < 256) {
    int m = tid & 15;
    int kb = tid >> 4;          // 0..15
    if (g * 16 + m < n) {
      short8 v;
      #pragma unroll
      for (int j = 0; j < 8; j++) v[j] = f2bf(M[m][kb * 8 + j]);
      *(short8*)(mAF + (size_t)g * 2048 + kb * 128 + m * 8) = v;
    }
  }
}

// ---------------- MFMA GEMM: y = relu([mean|x] @ [Wl;Wr] + b) -> AF + rm bf16 ----------------
__global__ __launch_bounds__(256) void k_gemm(
    const short* __restrict__ mAF0, const short* __restrict__ mAF1,
    const short* __restrict__ xAF0, const short* __restrict__ xAF1,
    const short* __restrict__ Wf,       // layer base: [2 types][65536]
    const float* __restrict__ bl,       // layer base: [2 types][128]
    short* __restrict__ obf0, short* __restrict__ obf1,
    short* __restrict__ oAF0, short* __restrict__ oAF1, int n)
{
  __shared__ __align__(16) char smem[32768];
  short* WfL = (short*)smem;            // [2][8192] dbuf during K-loop
  float* S   = (float*)smem;            // [128][64] epilogue scratch (after loop)

  int tid = (int)threadIdx.x;
  int l = tid & 63;
  int wv = tid >> 6;
  int bx = (int)blockIdx.x;
  int t = bx & 1;
  int tile = bx >> 1;
  int row0 = tile * 128;
  int g0 = tile * 8;

  const short* mAF = t ? mAF1 : mAF0;
  const short* xAF = t ? xAF1 : xAF0;
  const short* Wc  = Wf + (size_t)t * 65536;
  const float* bias = bl + t * FD;
  short* obf = t ? obf1 : obf0;
  short* oAF = t ? oAF1 : oAF0;

  int rhalf = wv & 1;
  int chalf = wv >> 1;
  int laneoff = (l >> 4) * 128 + (l & 15) * 8;

  auto stageW = [&](int ks, int buf) {
    const short* src = Wc + ks * 8192 + wv * 2048;
    short* dst = WfL + buf * 8192 + wv * 2048;
    #pragma unroll
    for (int i = 0; i < 4; i++) {
      __builtin_amdgcn_global_load_lds(
          (const __attribute__((address_space(1))) void*)(src + i * 512 + l * 8),
          (__attribute__((address_space(3))) void*)(dst + i * 512),
          16, 0, 0);
    }
  };

  floatx4 acc[4][4];
  #pragma unroll
  for (int i = 0; i < 4; i++)
    #pragma unroll
    for (int q = 0; q < 4; q++) acc[i][q] = (floatx4)0.f;

  short8 Acur[4], Anext[4];
  auto loadA = [&](int ks, short8* A) {
    const short* Ab = (ks < 4 ? mAF : xAF) + (ks & 3) * 512;
    #pragma unroll
    for (int i = 0; i < 4; i++) {
      int g = g0 + rhalf * 4 + i;
      A[i] = *(const short8*)(Ab + (size_t)g * 2048 + laneoff);
    }
  };

  stageW(0, 0);
  loadA(0, Acur);
  for (int ks = 0; ks < 8; ks++) {
    int buf = ks & 1;
    __syncthreads();
    if (ks < 7) { stageW(ks + 1, buf ^ 1); loadA(ks + 1, Anext); }
    const short* WB = WfL + buf * 8192;
    #pragma unroll
    for (int q = 0; q < 4; q++) {
      int nt = chalf * 4 + q;
      short8 whi = *(const short8*)(WB + nt * 512 + l * 8);
      short8 wlo = *(const short8*)(WB + 4096 + nt * 512 + l * 8);
      #pragma unroll
      for (int i = 0; i < 4; i++) {
        acc[i][q] = __builtin_amdgcn_mfma_f32_16x16x32_bf16(Acur[i], whi, acc[i][q], 0, 0, 0);
        acc[i][q] = __builtin_amdgcn_mfma_f32_16x16x32_bf16(Acur[i], wlo, acc[i][q], 0, 0, 0);
      }
    }
    #pragma unroll
    for (int i = 0; i < 4; i++) Acur[i] = Anext[i];
  }

  // bias + relu in-register
  #pragma unroll
  for (int q = 0; q < 4; q++) {
    int col = chalf * 64 + q * 16 + (l & 15);
    float b = bias[col];
    #pragma unroll
    for (int i = 0; i < 4; i++)
      #pragma unroll
      for (int r = 0; r < 4; r++)
        acc[i][q][r] = fmaxf(acc[i][q][r] + b, 0.f);
  }

  // emit AF bf16 + row-major bf16 via LDS transpose, one 64-col half at a time
  #pragma unroll
  for (int ph = 0; ph < 2; ph++) {
    __syncthreads();
    if (chalf == ph) {
      #pragma unroll
      for (int i = 0; i < 4; i++)
        #pragma unroll
        for (int q = 0; q < 4; q++)
          #pragma unroll
          for (int r = 0; r < 4; r++)
            S[(rhalf * 64 + i * 16 + (l >> 4) * 4 + r) * 64 + q * 16 + (l & 15)] = acc[i][q][r];
    }
    __syncthreads();
    #pragma unroll
    for (int it = 0; it < 4; it++) {
      int u = it * 256 + tid;
      int m = u & 15;
      int kb = (u >> 4) & 7;
      int grp = u >> 7;                    // 0..7
      int rl = grp * 16 + m;
      if (row0 + rl < n) {
        short8 s;
        #pragma unroll
        for (int j = 0; j < 8; j++) s[j] = f2bf(S[rl * 64 + kb * 8 + j]);
        *(short8*)(oAF + (size_t)(g0 + grp) * 2048 + (ph * 8 + kb) * 128 + m * 8) = s;
        *(short8*)(obf + (size_t)(row0 + rl) * FD + ph * 64 + kb * 8) = s;
      }
    }
  }
}

// ---------------- graph mean-pool from bf16 rows ----------------
__global__ __launch_bounds__(256) void k_pool(
    const unsigned short* __restrict__ x0, const unsigned short* __restrict__ x1,
    const int* __restrict__ b0, const int* __restrict__ b1,
    float* __restrict__ pool, float* __restrict__ pcnt, int n) {
  int bx = (int)blockIdx.x;
  int t = bx & 1;
  const unsigned short* x = t ? x1 : x0;
  const int* batch = t ? b1 : b0;
  float* pl = pool + t * NG * FD;
  float* pc = pcnt + t * NG;
  int tid = (int)threadIdx.x;
  int c4 = (tid & 31) * 4;
  int rs = tid >> 5;
  int start = (bx >> 1) * 128;
  int end = min(start + 128, n);
  if (start >= end) return;

  float4 acc = make_float4(0.f, 0.f, 0.f, 0.f);
  float cnt = 0.f;
  auto flush = [&](int g) {
    atomicAdd(&pl[g * FD + c4 + 0], acc.x);
    atomicAdd(&pl[g * FD + c4 + 1], acc.y);
    atomicAdd(&pl[g * FD + c4 + 2], acc.z);
    atomicAdd(&pl[g * FD + c4 + 3], acc.w);
    if ((tid & 31) == 0) atomicAdd(&pc[g], cnt);
  };

  int gfirst = batch[start];
  int glast = batch[end - 1];
  if (gfirst == glast) {
    for (int i = start + rs; i < end; i += 8) {
      ushort4 u = *(const ushort4*)&x[(size_t)i * FD + c4];
      acc.x += bfu(u.x); acc.y += bfu(u.y); acc.z += bfu(u.z); acc.w += bfu(u.w);
      cnt += 1.f;
    }
    flush(gfirst);
  } else {
    int curg = -1;
    for (int i = start + rs; i < end; i += 8) {
      int g = batch[i];
      if (g != curg) {
        if (curg >= 0) flush(curg);
        curg = g;
        acc = make_float4(0.f, 0.f, 0.f, 0.f);
        cnt = 0.f;
      }
      ushort4 u = *(const ushort4*)&x[(size_t)i * FD + c4];
      acc.x += bfu(u.x); acc.y += bfu(u.y); acc.z += bfu(u.z); acc.w += bfu(u.w);
      cnt += 1.f;
    }
    if (curg >= 0) flush(curg);
  }
}

// ---------------- head ----------------
__global__ void k_final(const float* __restrict__ pool, const float* __restrict__ pcnt,
                        const float* __restrict__ linW, const float* __restrict__ linb,
                        float* __restrict__ out) {
  int tid = (int)threadIdx.x;
  if (tid < NG * 2) {
    int g = tid >> 1, o = tid & 1;
    float s = linb[o];
    for (int t = 0; t < 2; t++) {
      float inv = 1.f / fmaxf(pcnt[t * NG + g], 1.f);
      for (int d = 0; d < FD; d++) {
        float h = pool[(t * NG + g) * FD + d] * inv;
        s = fmaf(h, linW[(t * FD + d) * 2 + o], s);
      }
    }
    out[g * 2 + o] = s;
  }
}

extern "C" void kernel_launch(void* const* d_in, const int* in_sizes, int n_in,
                              void* d_out, int out_size, void* d_ws, size_t ws_size,
                              hipStream_t stream) {
  const float* x_in[2] = {(const float*)d_in[0], (const float*)d_in[1]};
  const float* Wl   = (const float*)d_in[2];
  const float* bl   = (const float*)d_in[3];
  const float* Wr   = (const float*)d_in[4];
  const float* linW = (const float*)d_in[5];
  const float* linb = (const float*)d_in[6];
  const int* edges[2] = {(const int*)d_in[7], (const int*)d_in[8]};
  const int* batch[2] = {(const int*)d_in[9], (const int*)d_in[10]};

  const int N = in_sizes[0] / FD;    // 50000
  const int E = in_sizes[7] / 2;     // 800000
  const int NGRP = (N + 15) / 16;    // 3125
  const int NTILE = (N + 127) / 128; // 391
  const int NBUCK = (N + 255) / 256; // 196
  const int CAP = 5120;              // per-bucket capacity (avg ~4096)
  const size_t AFG = (size_t)(NTILE * 8 + 8) * 2048; // AF shorts

  // ---- workspace layout (512B aligned) ----
  char* p = (char*)d_ws;
  auto alloc = [&](size_t bytes) -> char* {
    char* r = p; p += (bytes + 511) & ~(size_t)511; return r;
  };
  int* gcount  = (int*)alloc(2 * 256 * 4);
  float* pool  = (float*)alloc(2 * NG * FD * 4);
  float* pcnt  = (float*)alloc(2 * NG * 4);
  size_t zero_bytes = (size_t)(p - (char*)d_ws);       // gcount+pool+pcnt
  int* off[2];  off[0]  = (int*)alloc((size_t)N * 4); off[1]  = (int*)alloc((size_t)N * 4);
  int* deg[2];  deg[0]  = (int*)alloc((size_t)N * 4); deg[1]  = (int*)alloc((size_t)N * 4);
  int* buckets = (int*)alloc((size_t)2 * NBUCK * CAP * 4);
  int* csr[2];  csr[0]  = (int*)alloc((size_t)NBUCK * CAP * 4);
                csr[1]  = (int*)alloc((size_t)NBUCK * CAP * 4);
  short* Wf    = (short*)alloc((size_t)6 * 65536 * 2);
  short* mAF[2]; mAF[0] = (short*)alloc(AFG * 2); mAF[1] = (short*)alloc(AFG * 2);
  short* xAF[2][2];
  for (int t = 0; t < 2; t++)
    for (int b = 0; b < 2; b++) xAF[t][b] = (short*)alloc(AFG * 2);
  short* xbf[2][2];
  for (int t = 0; t < 2; t++)
    for (int b = 0; b < 2; b++) xbf[t][b] = (short*)alloc((size_t)N * FD * 2);
  if ((size_t)(p - (char*)d_ws) > ws_size) return;     // insufficient workspace

  hipMemsetAsync(d_ws, 0, zero_bytes, stream);

  // conversions + CSR build
  k_wconv<<<(6 * 8192 + 255) / 256, 256, 0, stream>>>(Wl, Wr, Wf);
  k_xconv<<<2 * NGRP, 256, 0, stream>>>(x_in[0], x_in[1],
                                        xAF[0][0], xAF[1][0], xbf[0][0], xbf[1][0], N);
  int bblocks = 2 * ((E + 4095) / 4096);
  k_bucket<<<bblocks, 256, 0, stream>>>(edges[0], edges[1], gcount, buckets, E, NBUCK, CAP);
  k_csr<<<2 * NBUCK, 256, 0, stream>>>(gcount, buckets, csr[0], csr[1],
                                       off[0], off[1], deg[0], deg[1], NBUCK, CAP, N);

  int pp = 0;
  for (int l = 0; l < NL; l++) {
    k_agg<<<2 * NGRP, 512, 0, stream>>>(
        (const unsigned short*)xbf[0][pp], (const unsigned short*)xbf[1][pp],
        csr[0], csr[1], off[0], off[1], deg[0], deg[1], mAF[0], mAF[1], N);
    k_gemm<<<2 * NTILE, 256, 0, stream>>>(
        mAF[0], mAF[1], xAF[0][pp], xAF[1][pp],
        Wf + (size_t)l * 2 * 65536, bl + (size_t)l * 2 * FD,
        xbf[0][pp ^ 1], xbf[1][pp ^ 1], xAF[0][pp ^ 1], xAF[1][pp ^ 1], N);
    pp ^= 1;
  }

  int pblocks = 2 * ((N + 127) / 128);
  k_pool<<<pblocks, 256, 0, stream>>>(
      (const unsigned short*)xbf[0][pp], (const unsigned short*)xbf[1][pp],
      batch[0], batch[1], pool, pcnt, N);
  k_final<<<1, 64, 0, stream>>>(pool, pcnt, linW, linb, (float*)d_out);
}

// Round 7
// 447.808 us; speedup vs baseline: 41.5096x; 1.0446x over previous
//
#include <hip/hip_runtime.h>
#include <hip/hip_bf16.h>
#include <cstdint>
#include <cstddef>

static constexpr int FD = 128;   // feature dim
static constexpr int NG = 16;    // graphs per batch
static constexpr int NL = 3;     // layers

typedef __attribute__((ext_vector_type(8))) short short8;
typedef __attribute__((ext_vector_type(4))) float floatx4;

__device__ __forceinline__ short f2bf(float v) {
  union { __hip_bfloat16 b; short s; } u;
  u.b = __float2bfloat16(v);
  return u.s;
}
__device__ __forceinline__ float bfu(unsigned short u) {
  return __uint_as_float((unsigned int)u << 16);
}

// ---------------- pass A: bucket edges by dst>>8, LDS-sorted staging ----------------
// entry = src | (dst<<16)  (requires N <= 65536)
__global__ __launch_bounds__(256) void k_bucket(
    const int* __restrict__ e0, const int* __restrict__ e1,
    int* __restrict__ gcount, int* __restrict__ buckets,
    int E, int NBUCK, int CAP)
{
  __shared__ int hist[256], lexcl[256], gbase[256], wcur[256];
  __shared__ int staged[4096];
  __shared__ int wsum[4];
  __shared__ int totalS;
  int tid = (int)threadIdx.x;
  int bx = (int)blockIdx.x;
  int t = bx & 1;
  int chunk = (bx >> 1) * 4096;
  const int* eg = t ? e1 : e0;
  hist[tid] = 0;
  __syncthreads();
  unsigned int ent[16];
  #pragma unroll
  for (int k = 0; k < 16; k++) {
    int i = chunk + k * 256 + tid;
    if (i < E) {
      unsigned int src = (unsigned int)eg[i];
      unsigned int dst = (unsigned int)eg[E + i];
      ent[k] = src | (dst << 16);
      atomicAdd(&hist[dst >> 8], 1);
    } else ent[k] = 0xFFFFFFFFu;
  }
  __syncthreads();
  // block scan of hist[256]
  int lane = tid & 63, wv = tid >> 6;
  int v = hist[tid];
  int sc = v;
  #pragma unroll
  for (int d = 1; d < 64; d <<= 1) {
    int tt = __shfl_up(sc, d, 64);
    if (lane >= d) sc += tt;
  }
  if (lane == 63) wsum[wv] = sc;
  __syncthreads();
  int wpre = 0;
  for (int w = 0; w < wv; w++) wpre += wsum[w];
  int excl = wpre + sc - v;
  lexcl[tid] = excl;
  wcur[tid] = excl;
  gbase[tid] = v ? atomicAdd(&gcount[t * 256 + tid], v) : 0;
  if (tid == 255) totalS = excl + v;
  __syncthreads();
  #pragma unroll
  for (int k = 0; k < 16; k++) {
    if (ent[k] != 0xFFFFFFFFu) {
      int b = ent[k] >> 24;
      int pos = atomicAdd(&wcur[b], 1);
      staged[pos] = (int)ent[k];
    }
  }
  __syncthreads();
  int total = totalS;
  for (int j = tid; j < total; j += 256) {
    unsigned int e = (unsigned int)staged[j];
    int b = e >> 24;
    int gp = gbase[b] + (j - lexcl[b]);
    if (gp < CAP) buckets[((size_t)t * NBUCK + b) * CAP + gp] = (int)e;
  }
}

// ---------------- pass B: per-bucket deg/off/csr with LDS atomics only ----------------
__global__ __launch_bounds__(256) void k_csr(
    const int* __restrict__ gcount, const int* __restrict__ buckets,
    unsigned short* __restrict__ csr0, unsigned short* __restrict__ csr1,
    int* __restrict__ off0, int* __restrict__ off1,
    int* __restrict__ deg0, int* __restrict__ deg1,
    int NBUCK, int CAP, int n)
{
  __shared__ int hist[256], wcur[256], wsum[4];
  int tid = (int)threadIdx.x;
  int bx = (int)blockIdx.x;
  int t = bx & 1;
  int b = bx >> 1;
  int cnt = gcount[t * 256 + b];
  if (cnt > CAP) cnt = CAP;
  const int* base = buckets + ((size_t)t * NBUCK + b) * CAP;
  unsigned short* csr = t ? csr1 : csr0;
  int* off = t ? off1 : off0;
  int* deg = t ? deg1 : deg0;
  hist[tid] = 0;
  __syncthreads();
  for (int j = tid; j < cnt; j += 256)
    atomicAdd(&hist[((unsigned int)base[j] >> 16) & 255], 1);
  __syncthreads();
  int lane = tid & 63, wv = tid >> 6;
  int v = hist[tid];
  int sc = v;
  #pragma unroll
  for (int d = 1; d < 64; d <<= 1) {
    int tt = __shfl_up(sc, d, 64);
    if (lane >= d) sc += tt;
  }
  if (lane == 63) wsum[wv] = sc;
  __syncthreads();
  int wpre = 0;
  for (int w = 0; w < wv; w++) wpre += wsum[w];
  int excl = wpre + sc - v;
  wcur[tid] = excl;
  int node = b * 256 + tid;
  if (node < n) { deg[node] = v; off[node] = b * CAP + excl; }
  __syncthreads();
  for (int j = tid; j < cnt; j += 256) {
    unsigned int e = (unsigned int)base[j];
    int ld = (e >> 16) & 255;
    int pos = atomicAdd(&wcur[ld], 1);
    csr[b * CAP + pos] = (unsigned short)(e & 0xFFFFu);
  }
}

// ---------------- W -> fragment-layout bf16 hi/lo ----------------
__global__ void k_wconv(const float* __restrict__ Wl, const float* __restrict__ Wr,
                        short* __restrict__ Wf) {
  int u = blockIdx.x * blockDim.x + threadIdx.x;
  if (u >= 6 * 8192) return;
  int combo = u >> 13;
  int r = u & 8191;
  int l  = r & 63;
  int nt = (r >> 6) & 7;
  int h  = (r >> 9) & 1;
  int ks = r >> 10;
  short8 s;
  #pragma unroll
  for (int j = 0; j < 8; j++) {
    int k = ks * 32 + (l >> 4) * 8 + j;
    int n = nt * 16 + (l & 15);
    float w = (k < FD) ? Wl[((size_t)combo * FD + k) * FD + n]
                       : Wr[((size_t)combo * FD + (k - FD)) * FD + n];
    __hip_bfloat16 hb = __float2bfloat16(w);
    if (h == 0) {
      union { __hip_bfloat16 b; short t; } uu; uu.b = hb; s[j] = uu.t;
    } else {
      float hf = __bfloat162float(hb);
      s[j] = f2bf(w - hf);
    }
  }
  *(short8*)(Wf + (size_t)combo * 65536 + (size_t)r * 8) = s;
}

// ---------------- x (fp32) -> AF bf16 + row-major bf16 ----------------
__global__ __launch_bounds__(256) void k_xconv(
    const float* __restrict__ x0, const float* __restrict__ x1,
    short* __restrict__ a0, short* __restrict__ a1,
    short* __restrict__ r0, short* __restrict__ r1, int n) {
  int bx = blockIdx.x;
  int t = bx & 1;
  int g = bx >> 1;
  const float* x = t ? x1 : x0;
  short* a = t ? a1 : a0;
  short* rm = t ? r1 : r0;
  int tid = (int)threadIdx.x;
  int m = tid & 15;
  int kb = tid >> 4;          // 0..15
  int node = g * 16 + m;
  if (node >= n) return;
  const float* src = x + (size_t)node * FD + kb * 8;
  short8 s;
  #pragma unroll
  for (int j = 0; j < 8; j++) s[j] = f2bf(src[j]);
  *(short8*)(a + (size_t)g * 2048 + kb * 128 + m * 8) = s;
  *(short8*)(rm + (size_t)node * FD + kb * 8) = s;
}

// ---------------- neighbor mean from bf16 rows -> AF bf16 ----------------
__global__ __launch_bounds__(512) void k_agg(
    const unsigned short* __restrict__ x0, const unsigned short* __restrict__ x1,
    const unsigned short* __restrict__ csr0, const unsigned short* __restrict__ csr1,
    const int* __restrict__ off0, const int* __restrict__ off1,
    const int* __restrict__ deg0, const int* __restrict__ deg1,
    short* __restrict__ m0, short* __restrict__ m1, int n)
{
  __shared__ float M[16][132];
  int bx = blockIdx.x;
  int t = bx & 1;
  int g = bx >> 1;
  const unsigned short* x = t ? x1 : x0;
  const unsigned short* csr = t ? csr1 : csr0;
  const int* off  = t ? off1 : off0;
  const int* deg  = t ? deg1 : deg0;
  short* mAF      = t ? m1 : m0;
  int tid = (int)threadIdx.x;
  int s = tid >> 5;             // node slot 0..15
  int tx = tid & 31;
  int c4 = tx * 4;
  int node = g * 16 + s;
  if (node < n) {
    int o = off[node], d = deg[node];
    float a0 = 0.f, a1 = 0.f, a2 = 0.f, a3 = 0.f;
    for (int k0 = 0; k0 < d; k0 += 32) {
      int idx = (k0 + tx < d) ? (int)csr[o + k0 + tx] : 0;
      int mm = min(32, d - k0);
      int j = 0;
      for (; j + 8 <= mm; j += 8) {
        int s0 = __shfl(idx, j + 0, 32);
        int s1 = __shfl(idx, j + 1, 32);
        int s2 = __shfl(idx, j + 2, 32);
        int s3 = __shfl(idx, j + 3, 32);
        int s4 = __shfl(idx, j + 4, 32);
        int s5 = __shfl(idx, j + 5, 32);
        int s6 = __shfl(idx, j + 6, 32);
        int s7 = __shfl(idx, j + 7, 32);
        ushort4 u0 = *(const ushort4*)&x[(size_t)s0 * FD + c4];
        ushort4 u1 = *(const ushort4*)&x[(size_t)s1 * FD + c4];
        ushort4 u2 = *(const ushort4*)&x[(size_t)s2 * FD + c4];
        ushort4 u3 = *(const ushort4*)&x[(size_t)s3 * FD + c4];
        ushort4 u4 = *(const ushort4*)&x[(size_t)s4 * FD + c4];
        ushort4 u5 = *(const ushort4*)&x[(size_t)s5 * FD + c4];
        ushort4 u6 = *(const ushort4*)&x[(size_t)s6 * FD + c4];
        ushort4 u7 = *(const ushort4*)&x[(size_t)s7 * FD + c4];
        a0 += ((bfu(u0.x) + bfu(u1.x)) + (bfu(u2.x) + bfu(u3.x)))
            + ((bfu(u4.x) + bfu(u5.x)) + (bfu(u6.x) + bfu(u7.x)));
        a1 += ((bfu(u0.y) + bfu(u1.y)) + (bfu(u2.y) + bfu(u3.y)))
            + ((bfu(u4.y) + bfu(u5.y)) + (bfu(u6.y) + bfu(u7.y)));
        a2 += ((bfu(u0.z) + bfu(u1.z)) + (bfu(u2.z) + bfu(u3.z)))
            + ((bfu(u4.z) + bfu(u5.z)) + (bfu(u6.z) + bfu(u7.z)));
        a3 += ((bfu(u0.w) + bfu(u1.w)) + (bfu(u2.w) + bfu(u3.w)))
            + ((bfu(u4.w) + bfu(u5.w)) + (bfu(u6.w) + bfu(u7.w)));
      }
      for (; j < mm; j++) {
        int si = __shfl(idx, j, 32);
        ushort4 u = *(const ushort4*)&x[(size_t)si * FD + c4];
        a0 += bfu(u.x); a1 += bfu(u.y); a2 += bfu(u.z); a3 += bfu(u.w);
      }
    }
    float inv = 1.f / fmaxf((float)d, 1.f);
    M[s][c4 + 0] = a0 * inv;
    M[s][c4 + 1] = a1 * inv;
    M[s][c4 + 2] = a2 * inv;
    M[s][c4 + 3] = a3 * inv;
  }
  __syncthreads();
  if (tid < 256) {
    int m = tid & 15;
    int kb = tid >> 4;          // 0..15
    if (g * 16 + m < n) {
      short8 v;
      #pragma unroll
      for (int j = 0; j < 8; j++) v[j] = f2bf(M[m][kb * 8 + j]);
      *(short8*)(mAF + (size_t)g * 2048 + kb * 128 + m * 8) = v;
    }
  }
}

// ---------------- MFMA GEMM: y = relu([mean|x] @ [Wl;Wr] + b) -> AF + rm bf16 ----------------
__global__ __launch_bounds__(256) void k_gemm(
    const short* __restrict__ mAF0, const short* __restrict__ mAF1,
    const short* __restrict__ xAF0, const short* __restrict__ xAF1,
    const short* __restrict__ Wf,       // layer base: [2 types][65536]
    const float* __restrict__ bl,       // layer base: [2 types][128]
    short* __restrict__ obf0, short* __restrict__ obf1,
    short* __restrict__ oAF0, short* __restrict__ oAF1, int n)
{
  __shared__ __align__(16) char smem[32768];
  short* WfL = (short*)smem;            // [2][8192] dbuf during K-loop
  float* S   = (float*)smem;            // [128][64] epilogue scratch (after loop)

  int tid = (int)threadIdx.x;
  int l = tid & 63;
  int wv = tid >> 6;
  int bx = (int)blockIdx.x;
  int t = bx & 1;
  int tile = bx >> 1;
  int row0 = tile * 128;
  int g0 = tile * 8;

  const short* mAF = t ? mAF1 : mAF0;
  const short* xAF = t ? xAF1 : xAF0;
  const short* Wc  = Wf + (size_t)t * 65536;
  const float* bias = bl + t * FD;
  short* obf = t ? obf1 : obf0;
  short* oAF = t ? oAF1 : oAF0;

  int rhalf = wv & 1;
  int chalf = wv >> 1;
  int laneoff = (l >> 4) * 128 + (l & 15) * 8;

  auto stageW = [&](int ks, int buf) {
    const short* src = Wc + ks * 8192 + wv * 2048;
    short* dst = WfL + buf * 8192 + wv * 2048;
    #pragma unroll
    for (int i = 0; i < 4; i++) {
      __builtin_amdgcn_global_load_lds(
          (const __attribute__((address_space(1))) void*)(src + i * 512 + l * 8),
          (__attribute__((address_space(3))) void*)(dst + i * 512),
          16, 0, 0);
    }
  };

  floatx4 acc[4][4];
  #pragma unroll
  for (int i = 0; i < 4; i++)
    #pragma unroll
    for (int q = 0; q < 4; q++) acc[i][q] = (floatx4)0.f;

  short8 Acur[4], Anext[4];
  auto loadA = [&](int ks, short8* A) {
    const short* Ab = (ks < 4 ? mAF : xAF) + (ks & 3) * 512;
    #pragma unroll
    for (int i = 0; i < 4; i++) {
      int g = g0 + rhalf * 4 + i;
      A[i] = *(const short8*)(Ab + (size_t)g * 2048 + laneoff);
    }
  };

  stageW(0, 0);
  loadA(0, Acur);
  for (int ks = 0; ks < 8; ks++) {
    int buf = ks & 1;
    __syncthreads();
    if (ks < 7) { stageW(ks + 1, buf ^ 1); loadA(ks + 1, Anext); }
    const short* WB = WfL + buf * 8192;
    #pragma unroll
    for (int q = 0; q < 4; q++) {
      int nt = chalf * 4 + q;
      short8 whi = *(const short8*)(WB + nt * 512 + l * 8);
      short8 wlo = *(const short8*)(WB + 4096 + nt * 512 + l * 8);
      #pragma unroll
      for (int i = 0; i < 4; i++) {
        acc[i][q] = __builtin_amdgcn_mfma_f32_16x16x32_bf16(Acur[i], whi, acc[i][q], 0, 0, 0);
        acc[i][q] = __builtin_amdgcn_mfma_f32_16x16x32_bf16(Acur[i], wlo, acc[i][q], 0, 0, 0);
      }
    }
    #pragma unroll
    for (int i = 0; i < 4; i++) Acur[i] = Anext[i];
  }

  // bias + relu in-register
  #pragma unroll
  for (int q = 0; q < 4; q++) {
    int col = chalf * 64 + q * 16 + (l & 15);
    float b = bias[col];
    #pragma unroll
    for (int i = 0; i < 4; i++)
      #pragma unroll
      for (int r = 0; r < 4; r++)
        acc[i][q][r] = fmaxf(acc[i][q][r] + b, 0.f);
  }

  // emit AF bf16 + row-major bf16 via LDS transpose, one 64-col half at a time
  #pragma unroll
  for (int ph = 0; ph < 2; ph++) {
    __syncthreads();
    if (chalf == ph) {
      #pragma unroll
      for (int i = 0; i < 4; i++)
        #pragma unroll
        for (int q = 0; q < 4; q++)
          #pragma unroll
          for (int r = 0; r < 4; r++)
            S[(rhalf * 64 + i * 16 + (l >> 4) * 4 + r) * 64 + q * 16 + (l & 15)] = acc[i][q][r];
    }
    __syncthreads();
    #pragma unroll
    for (int it = 0; it < 4; it++) {
      int u = it * 256 + tid;
      int m = u & 15;
      int kb = (u >> 4) & 7;
      int grp = u >> 7;                    // 0..7
      int rl = grp * 16 + m;
      if (row0 + rl < n) {
        short8 s;
        #pragma unroll
        for (int j = 0; j < 8; j++) s[j] = f2bf(S[rl * 64 + kb * 8 + j]);
        *(short8*)(oAF + (size_t)(g0 + grp) * 2048 + (ph * 8 + kb) * 128 + m * 8) = s;
        *(short8*)(obf + (size_t)(row0 + rl) * FD + ph * 64 + kb * 8) = s;
      }
    }
  }
}

// ---------------- pool stage 1: dense per-chunk partials, no atomics ----------------
// part stride 272 floats: [run0 sums 128][run1 sums 128][g0,cnt0,g1,cnt1]
__global__ __launch_bounds__(256) void k_pool1(
    const unsigned short* __restrict__ x0, const unsigned short* __restrict__ x1,
    const int* __restrict__ b0, const int* __restrict__ b1,
    float* __restrict__ part, int n, int NCH) {
  __shared__ float R[8][128];
  __shared__ int sb;
  int bx = (int)blockIdx.x;
  int t = bx & 1;
  int ch = bx >> 1;
  const unsigned short* x = t ? x1 : x0;
  const int* batch = t ? b1 : b0;
  float* P = part + ((size_t)t * NCH + ch) * 272;
  int tid = (int)threadIdx.x;
  int tx = tid & 31, rs = tid >> 5;
  int c4 = tx * 4;
  int start = ch * 128;
  int end = min(start + 128, n);

  int g0 = batch[start];
  int g1 = batch[end - 1];
  int lo[2], hi[2];
  int nruns;
  if (g0 == g1) {
    lo[0] = start; hi[0] = end; nruns = 1;
  } else {
    if (tid == 0) sb = end;
    __syncthreads();
    for (int i = start + tid + 1; i < end; i += 256)
      if (batch[i] != batch[i - 1]) atomicMin(&sb, i);
    __syncthreads();
    int b = sb;
    lo[0] = start; hi[0] = b; lo[1] = b; hi[1] = end; nruns = 2;
  }

  for (int run = 0; run < nruns; run++) {
    float4 a = make_float4(0.f, 0.f, 0.f, 0.f);
    for (int i = lo[run] + rs; i < hi[run]; i += 8) {
      ushort4 u = *(const ushort4*)&x[(size_t)i * FD + c4];
      a.x += bfu(u.x); a.y += bfu(u.y); a.z += bfu(u.z); a.w += bfu(u.w);
    }
    *(float4*)&R[rs][c4] = a;
    __syncthreads();
    if (tid < 128) {
      float s = 0.f;
      #pragma unroll
      for (int r = 0; r < 8; r++) s += R[r][tid];
      P[run * 128 + tid] = s;
    }
    __syncthreads();
  }
  if (tid == 0) {
    P[256] = (float)g0;
    P[257] = (float)(hi[0] - lo[0]);
    P[258] = (nruns == 2) ? (float)g1 : -1.f;
    P[259] = (nruns == 2) ? (float)(hi[1] - lo[1]) : 0.f;
  }
}

// ---------------- pool stage 2: reduce chunk partials (few atomics) ----------------
__global__ __launch_bounds__(128) void k_pool2(
    const float* __restrict__ part, float* __restrict__ pool,
    float* __restrict__ pcnt, int NCH, int CPS) {
  int bx = (int)blockIdx.x;
  int t = bx & 1;
  int seg = bx >> 1;
  int c0 = seg * CPS;
  int c1 = min(c0 + CPS, NCH);
  int tid = (int)threadIdx.x;
  float* pl = pool + t * NG * FD;
  float* pc = pcnt + t * NG;
  float acc = 0.f, ccnt = 0.f;
  int curg = -1;
  for (int ch = c0; ch < c1; ch++) {
    const float* P = part + ((size_t)t * NCH + ch) * 272;
    #pragma unroll
    for (int r = 0; r < 2; r++) {
      int g = (int)P[256 + r * 2];
      if (g < 0) continue;
      if (g != curg) {
        if (curg >= 0) {
          atomicAdd(&pl[curg * FD + tid], acc);
          if (tid == 0) atomicAdd(&pc[curg], ccnt);
        }
        curg = g; acc = 0.f; ccnt = 0.f;
      }
      acc += P[r * 128 + tid];
      if (tid == 0) ccnt += P[257 + r * 2];
    }
  }
  if (curg >= 0) {
    atomicAdd(&pl[curg * FD + tid], acc);
    if (tid == 0) atomicAdd(&pc[curg], ccnt);
  }
}

// ---------------- head ----------------
__global__ void k_final(const float* __restrict__ pool, const float* __restrict__ pcnt,
                        const float* __restrict__ linW, const float* __restrict__ linb,
                        float* __restrict__ out) {
  int tid = (int)threadIdx.x;
  if (tid < NG * 2) {
    int g = tid >> 1, o = tid & 1;
    float s = linb[o];
    for (int t = 0; t < 2; t++) {
      float inv = 1.f / fmaxf(pcnt[t * NG + g], 1.f);
      for (int d = 0; d < FD; d++) {
        float h = pool[(t * NG + g) * FD + d] * inv;
        s = fmaf(h, linW[(t * FD + d) * 2 + o], s);
      }
    }
    out[g * 2 + o] = s;
  }
}

extern "C" void kernel_launch(void* const* d_in, const int* in_sizes, int n_in,
                              void* d_out, int out_size, void* d_ws, size_t ws_size,
                              hipStream_t stream) {
  const float* x_in[2] = {(const float*)d_in[0], (const float*)d_in[1]};
  const float* Wl   = (const float*)d_in[2];
  const float* bl   = (const float*)d_in[3];
  const float* Wr   = (const float*)d_in[4];
  const float* linW = (const float*)d_in[5];
  const float* linb = (const float*)d_in[6];
  const int* edges[2] = {(const int*)d_in[7], (const int*)d_in[8]};
  const int* batch[2] = {(const int*)d_in[9], (const int*)d_in[10]};

  const int N = in_sizes[0] / FD;    // 50000
  const int E = in_sizes[7] / 2;     // 800000
  const int NGRP = (N + 15) / 16;    // 3125
  const int NTILE = (N + 127) / 128; // 391
  const int NCH = (N + 127) / 128;   // 391
  const int NBUCK = (N + 255) / 256; // 196
  const int CAP = 5120;              // per-bucket capacity (avg ~4096)
  const size_t AFG = (size_t)(NTILE * 8 + 8) * 2048; // AF shorts

  // ---- workspace layout (512B aligned) ----
  char* p = (char*)d_ws;
  auto alloc = [&](size_t bytes) -> char* {
    char* r = p; p += (bytes + 511) & ~(size_t)511; return r;
  };
  int* gcount  = (int*)alloc(2 * 256 * 4);
  float* pool  = (float*)alloc(2 * NG * FD * 4);
  float* pcnt  = (float*)alloc(2 * NG * 4);
  size_t zero_bytes = (size_t)(p - (char*)d_ws);       // gcount+pool+pcnt
  int* off[2];  off[0]  = (int*)alloc((size_t)N * 4); off[1]  = (int*)alloc((size_t)N * 4);
  int* deg[2];  deg[0]  = (int*)alloc((size_t)N * 4); deg[1]  = (int*)alloc((size_t)N * 4);
  int* buckets = (int*)alloc((size_t)2 * NBUCK * CAP * 4);
  unsigned short* csr[2];
  csr[0] = (unsigned short*)alloc((size_t)NBUCK * CAP * 2);
  csr[1] = (unsigned short*)alloc((size_t)NBUCK * CAP * 2);
  float* part  = (float*)alloc((size_t)2 * NCH * 272 * 4);
  short* Wf    = (short*)alloc((size_t)6 * 65536 * 2);
  short* mAF[2]; mAF[0] = (short*)alloc(AFG * 2); mAF[1] = (short*)alloc(AFG * 2);
  short* xAF[2][2];
  for (int t = 0; t < 2; t++)
    for (int b = 0; b < 2; b++) xAF[t][b] = (short*)alloc(AFG * 2);
  short* xbf[2][2];
  for (int t = 0; t < 2; t++)
    for (int b = 0; b < 2; b++) xbf[t][b] = (short*)alloc((size_t)N * FD * 2);
  if ((size_t)(p - (char*)d_ws) > ws_size) return;     // insufficient workspace

  hipMemsetAsync(d_ws, 0, zero_bytes, stream);

  // conversions + CSR build
  k_wconv<<<(6 * 8192 + 255) / 256, 256, 0, stream>>>(Wl, Wr, Wf);
  k_xconv<<<2 * NGRP, 256, 0, stream>>>(x_in[0], x_in[1],
                                        xAF[0][0], xAF[1][0], xbf[0][0], xbf[1][0], N);
  int bblocks = 2 * ((E + 4095) / 4096);
  k_bucket<<<bblocks, 256, 0, stream>>>(edges[0], edges[1], gcount, buckets, E, NBUCK, CAP);
  k_csr<<<2 * NBUCK, 256, 0, stream>>>(gcount, buckets, csr[0], csr[1],
                                       off[0], off[1], deg[0], deg[1], NBUCK, CAP, N);

  int pp = 0;
  for (int l = 0; l < NL; l++) {
    k_agg<<<2 * NGRP, 512, 0, stream>>>(
        (const unsigned short*)xbf[0][pp], (const unsigned short*)xbf[1][pp],
        csr[0], csr[1], off[0], off[1], deg[0], deg[1], mAF[0], mAF[1], N);
    k_gemm<<<2 * NTILE, 256, 0, stream>>>(
        mAF[0], mAF[1], xAF[0][pp], xAF[1][pp],
        Wf + (size_t)l * 2 * 65536, bl + (size_t)l * 2 * FD,
        xbf[0][pp ^ 1], xbf[1][pp ^ 1], xAF[0][pp ^ 1], xAF[1][pp ^ 1], N);
    pp ^= 1;
  }

  k_pool1<<<2 * NCH, 256, 0, stream>>>(
      (const unsigned short*)xbf[0][pp], (const unsigned short*)xbf[1][pp],
      batch[0], batch[1], part, N, NCH);
  int CPS = (NCH + 7) / 8;
  k_pool2<<<16, 128, 0, stream>>>(part, pool, pcnt, NCH, CPS);
  k_final<<<1, 64, 0, stream>>>(pool, pcnt, linW, linb, (float*)d_out);
}